// Round 20
// baseline (652.299 us; speedup 1.0000x reference)
//
#include <hip/hip_runtime.h>

// ---------------- constants ----------------
constexpr int B = 2, S = 4096, D = 768, H = 12, DH = 64, BLK = 64, NB = 64, NKV = 8;
constexpr int F = 3072, NS = 8, M = B * S;            // M = 8192 tokens
constexpr int NCH = 4;                                 // dense split-K chunks
constexpr float SCALE = 0.125f;                        // 1/sqrt(64)
constexpr float L2E = 1.44269504088896f;               // log2(e)
constexpr long HD = (long)M * D;                       // 6291456 elems per [M,D] buffer

using u16 = unsigned short;
using u32 = unsigned int;
using bf16 = __bf16;
using bf16x8 = __attribute__((ext_vector_type(8))) bf16;
using f32x4 = __attribute__((ext_vector_type(4))) float;

// bf16 weight region layout (u16 counts): [qkv x6 DD][ao x2 DD][ff1 x2 DF][ff2 x2 FD]
constexpr long DD = (long)D * D;
constexpr long DF = (long)D * F;
constexpr long OFF_AO  = 6 * DD;
constexpr long OFF_FF1 = 8 * DD;
constexpr long OFF_FF2 = 8 * DD + 2 * DF;

__device__ __forceinline__ u16 f2bf(float x) {
  u32 u = __builtin_bit_cast(u32, x);
  u = (u + 0x7fffu + ((u >> 16) & 1u)) >> 16;
  return (u16)u;
}
__device__ __forceinline__ u32 pack2(float a, float b) {
  return (u32)f2bf(a) | ((u32)f2bf(b) << 16);
}
// fast tanh-gelu: 0.5x(1+tanh(u)) == x - x/(exp(2u)+1); inf-safe both tails
__device__ __forceinline__ float fast_gelu(float x) {
  float u = 0.7978845608028654f * (x + 0.044715f * x * x * x);
  float t = __expf(u + u);
  return x - x * __builtin_amdgcn_rcpf(t + 1.f);
}

// async 16B global -> LDS (dest = wave-uniform base + lane*16)
__device__ __forceinline__ void gload16(const void* g, void* l) {
  __builtin_amdgcn_global_load_lds(
      (const __attribute__((address_space(1))) u32*)g,
      (__attribute__((address_space(3))) u32*)l, 16, 0, 0);
}

// ---------------- weight transpose + cast: out[n][k] = bf16(in[k][n]) ----------------
__global__ __launch_bounds__(256) void wtrans_kern(
    const float* __restrict__ in, u16* __restrict__ out, int K, int N, long inz, long outz)
{
  in += (long)blockIdx.z * inz; out += (long)blockIdx.z * outz;
  __shared__ float T[32][33];
  const int n0 = blockIdx.x * 32, k0 = blockIdx.y * 32;
  const int c = threadIdx.x & 31, r8 = threadIdx.x >> 5;
  #pragma unroll
  for (int i = 0; i < 4; ++i)
    T[r8 + i * 8][c] = in[(long)(k0 + r8 + i * 8) * N + n0 + c];
  __syncthreads();
  #pragma unroll
  for (int i = 0; i < 4; ++i)
    out[(long)(n0 + r8 + i * 8) * K + k0 + c] = f2bf(T[c][r8 + i * 8]);
}

// ---------------- embedding + LN: wave-per-row, float4, no LDS/barrier ----------------
__global__ __launch_bounds__(256) void embed_ln_kern(
    const int* __restrict__ ids, const int* __restrict__ tt,
    const float* __restrict__ we, const float* __restrict__ pe, const float* __restrict__ te,
    const float* __restrict__ g, const float* __restrict__ bb,
    float* __restrict__ h, u16* __restrict__ hb)
{
  const long i = (long)blockIdx.x * 4 + (threadIdx.x >> 6);
  const int lane = threadIdx.x & 63;
  const int c = lane * 4;
  const int s = (int)(i & (S - 1));
  const long wo = (long)ids[i] * D;
  const long to = (long)tt[i] * D;
  const long po = (long)s * D;
  float4 x0, x1, x2;
  {
    float4 a0 = *(const float4*)(we + wo + c),       p0 = *(const float4*)(pe + po + c),
           t0 = *(const float4*)(te + to + c);
    float4 a1 = *(const float4*)(we + wo + c + 256), p1 = *(const float4*)(pe + po + c + 256),
           t1 = *(const float4*)(te + to + c + 256);
    float4 a2 = *(const float4*)(we + wo + c + 512), p2 = *(const float4*)(pe + po + c + 512),
           t2 = *(const float4*)(te + to + c + 512);
    x0 = make_float4(a0.x+p0.x+t0.x, a0.y+p0.y+t0.y, a0.z+p0.z+t0.z, a0.w+p0.w+t0.w);
    x1 = make_float4(a1.x+p1.x+t1.x, a1.y+p1.y+t1.y, a1.z+p1.z+t1.z, a1.w+p1.w+t1.w);
    x2 = make_float4(a2.x+p2.x+t2.x, a2.y+p2.y+t2.y, a2.z+p2.z+t2.z, a2.w+p2.w+t2.w);
  }
  float sm = x0.x+x0.y+x0.z+x0.w + x1.x+x1.y+x1.z+x1.w + x2.x+x2.y+x2.z+x2.w;
  float sq = x0.x*x0.x+x0.y*x0.y+x0.z*x0.z+x0.w*x0.w
           + x1.x*x1.x+x1.y*x1.y+x1.z*x1.z+x1.w*x1.w
           + x2.x*x2.x+x2.y*x2.y+x2.z*x2.z+x2.w*x2.w;
  #pragma unroll
  for (int o = 32; o; o >>= 1) { sm += __shfl_xor(sm, o); sq += __shfl_xor(sq, o); }
  const float mean = sm * (1.f / D);
  const float var  = sq * (1.f / D) - mean * mean;
  const float rs   = rsqrtf(var + 1e-12f);
  float4 g0 = *(const float4*)(g + c),  g1 = *(const float4*)(g + c + 256),
         g2 = *(const float4*)(g + c + 512);
  float4 b0 = *(const float4*)(bb + c), b1 = *(const float4*)(bb + c + 256),
         b2 = *(const float4*)(bb + c + 512);
  float* row = h + i * D;
  u16* rb = hb + i * D;
  float4 y0 = make_float4((x0.x-mean)*rs*g0.x+b0.x, (x0.y-mean)*rs*g0.y+b0.y,
                          (x0.z-mean)*rs*g0.z+b0.z, (x0.w-mean)*rs*g0.w+b0.w);
  float4 y1 = make_float4((x1.x-mean)*rs*g1.x+b1.x, (x1.y-mean)*rs*g1.y+b1.y,
                          (x1.z-mean)*rs*g1.z+b1.z, (x1.w-mean)*rs*g1.w+b1.w);
  float4 y2 = make_float4((x2.x-mean)*rs*g2.x+b2.x, (x2.y-mean)*rs*g2.y+b2.y,
                          (x2.z-mean)*rs*g2.z+b2.z, (x2.w-mean)*rs*g2.w+b2.w);
  *(float4*)(row + c)       = y0;
  *(float4*)(row + c + 256) = y1;
  *(float4*)(row + c + 512) = y2;
  *(uint2*)(rb + c)       = make_uint2(pack2(y0.x, y0.y), pack2(y0.z, y0.w));
  *(uint2*)(rb + c + 256) = make_uint2(pack2(y1.x, y1.y), pack2(y1.z, y1.w));
  *(uint2*)(rb + c + 512) = make_uint2(pack2(y2.x, y2.y), pack2(y2.z, y2.w));
}

// ---------------- LayerNorm: wave-per-row, float4, no LDS/barrier ----------------
__global__ __launch_bounds__(256) void ln_kern(
    float* __restrict__ h, const float* __restrict__ g, const float* __restrict__ bb,
    u16* __restrict__ hb)
{
  const long i = (long)blockIdx.x * 4 + (threadIdx.x >> 6);
  const int lane = threadIdx.x & 63;
  const int c = lane * 4;
  float* row = h + i * D;
  u16* rb = hb + i * D;
  float4 x0 = *(const float4*)(row + c);
  float4 x1 = *(const float4*)(row + c + 256);
  float4 x2 = *(const float4*)(row + c + 512);
  float sm = x0.x+x0.y+x0.z+x0.w + x1.x+x1.y+x1.z+x1.w + x2.x+x2.y+x2.z+x2.w;
  float sq = x0.x*x0.x+x0.y*x0.y+x0.z*x0.z+x0.w*x0.w
           + x1.x*x1.x+x1.y*x1.y+x1.z*x1.z+x1.w*x1.w
           + x2.x*x2.x+x2.y*x2.y+x2.z*x2.z+x2.w*x2.w;
  #pragma unroll
  for (int o = 32; o; o >>= 1) { sm += __shfl_xor(sm, o); sq += __shfl_xor(sq, o); }
  const float mean = sm * (1.f / D);
  const float var  = sq * (1.f / D) - mean * mean;
  const float rs   = rsqrtf(var + 1e-12f);
  float4 g0 = *(const float4*)(g + c),  g1 = *(const float4*)(g + c + 256),
         g2 = *(const float4*)(g + c + 512);
  float4 b0 = *(const float4*)(bb + c), b1 = *(const float4*)(bb + c + 256),
         b2 = *(const float4*)(bb + c + 512);
  float4 y0 = make_float4((x0.x-mean)*rs*g0.x+b0.x, (x0.y-mean)*rs*g0.y+b0.y,
                          (x0.z-mean)*rs*g0.z+b0.z, (x0.w-mean)*rs*g0.w+b0.w);
  float4 y1 = make_float4((x1.x-mean)*rs*g1.x+b1.x, (x1.y-mean)*rs*g1.y+b1.y,
                          (x1.z-mean)*rs*g1.z+b1.z, (x1.w-mean)*rs*g1.w+b1.w);
  float4 y2 = make_float4((x2.x-mean)*rs*g2.x+b2.x, (x2.y-mean)*rs*g2.y+b2.y,
                          (x2.z-mean)*rs*g2.z+b2.z, (x2.w-mean)*rs*g2.w+b2.w);
  *(float4*)(row + c)       = y0;
  *(float4*)(row + c + 256) = y1;
  *(float4*)(row + c + 512) = y2;
  *(uint2*)(rb + c)       = make_uint2(pack2(y0.x, y0.y), pack2(y0.z, y0.w));
  *(uint2*)(rb + c + 256) = make_uint2(pack2(y1.x, y1.y), pack2(y1.z, y1.w));
  *(uint2*)(rb + c + 512) = make_uint2(pack2(y2.x, y2.y), pack2(y2.z, y2.w));
}

// ---------------- bf16 MFMA GEMM: BK=64, 2-stage, counted vmcnt + raw barriers ------
// (round-10 core, best known)
__global__ __launch_bounds__(256) void mgemm_kern(
    const u16* __restrict__ A, const u16* __restrict__ Wt,
    const float* __restrict__ bias, void* __restrict__ Cv,
    int N, int K, long wz, long bz, long cz, int mode, int ksplit)
{
  const int z = blockIdx.z;
  int k0 = 0, kend = K;
  if (ksplit > 1) {
    const int kch = K / ksplit;
    k0 = z * kch; kend = k0 + kch;
  } else {
    Wt += (long)z * wz; bias += (long)z * bz;
  }
  const int gx = gridDim.x;
  const int nwg = gx * gridDim.y;
  int bid = blockIdx.y * gx + blockIdx.x;
  bid = (bid & 7) * (nwg >> 3) + (bid >> 3);
  const long bm = (long)(bid / gx) * 128;
  const int bn = (bid % gx) * 128;

  const int tid = threadIdx.x;
  const int lane = tid & 63, w = tid >> 6;
  const int wm = w >> 1, wn = w & 1;
  const int ls = lane >> 4, lr = lane & 15;

  __shared__ u16 LB[32768];
  u16* const St0 = LB;
  u16* const St1 = LB + 16384;

  f32x4 acc[4][4];
  #pragma unroll
  for (int i = 0; i < 4; ++i)
    #pragma unroll
    for (int j = 0; j < 4; ++j)
      acc[i][j] = (f32x4){0.f, 0.f, 0.f, 0.f};

  auto STAGE = [&](u16* buf, int kk) {
    #pragma unroll
    for (int c = 0; c < 4; ++c) {
      const int n = (w * 4 + c) * 64 + lane;
      const int row = n >> 3;
      const int kc2 = (n & 7) ^ (row & 7);
      gload16(A  + (bm + row) * K + kk + kc2 * 8, buf + (w * 4 + c) * 512);
      gload16(Wt + (long)(bn + row) * K + kk + kc2 * 8, buf + 8192 + (w * 4 + c) * 512);
    }
  };

  STAGE(St0, k0);
  int cur = 0;
  for (int kk = k0; kk < kend; kk += 64) {
    if (kk + 64 < kend) {
      STAGE(cur ? St0 : St1, kk + 64);
      asm volatile("s_waitcnt vmcnt(8)" ::: "memory");
    } else {
      asm volatile("s_waitcnt vmcnt(0)" ::: "memory");
    }
    __builtin_amdgcn_s_barrier();
    __builtin_amdgcn_sched_barrier(0);
    const u16* AsL = cur ? St1 : St0;
    const u16* BsL = AsL + 8192;
    __builtin_amdgcn_s_setprio(1);
    #pragma unroll
    for (int ks = 0; ks < 2; ++ks) {
      bf16x8 af[4], bv[4];
      const int kc = ks * 4 + ls;
      const int sw = (kc ^ (lr & 7)) << 3;
      #pragma unroll
      for (int mf = 0; mf < 4; ++mf)
        af[mf] = *(const bf16x8*)&AsL[(wm * 64 + mf * 16 + lr) * 64 + sw];
      #pragma unroll
      for (int nf = 0; nf < 4; ++nf)
        bv[nf] = *(const bf16x8*)&BsL[(wn * 64 + nf * 16 + lr) * 64 + sw];
      #pragma unroll
      for (int mf = 0; mf < 4; ++mf)
        #pragma unroll
        for (int nf = 0; nf < 4; ++nf)
          acc[mf][nf] = __builtin_amdgcn_mfma_f32_16x16x32_bf16(
              af[mf], bv[nf], acc[mf][nf], 0, 0, 0);
    }
    __builtin_amdgcn_s_setprio(0);
    __builtin_amdgcn_s_barrier();
    cur ^= 1;
  }

  float* Cf = (float*)Cv + (long)z * cz;
  u16*   Cu = (u16*)Cv  + (long)z * cz;
  const int r0 = ls * 4;
  const bool addb = (ksplit == 1) || (z == 0);

  if (mode == 1 || (mode == 4 && bn < 1536)) {
    const int t = (mode == 4) ? (bn / 768) : 0;
    const int cl0 = (mode == 4) ? (bn - t * 768) : bn;
    const int Nt = (mode == 4) ? 768 : N;
    u16* Cd = (mode == 4) ? (Cu + (long)t * HD) : Cu;
    #pragma unroll
    for (int nf = 0; nf < 4; ++nf) {
      const int col = wn * 64 + nf * 16 + lr;
      const float bvv = bias[bn + col];
      #pragma unroll
      for (int mf = 0; mf < 4; ++mf) {
        #pragma unroll
        for (int r = 0; r < 4; ++r) {
          const int rowl = wm * 64 + mf * 16 + r0 + r;
          float vv = acc[mf][nf][r] + bvv;
          if (mode == 1) vv = fast_gelu(vv);
          LB[rowl * 128 + (col ^ ((rowl & 7) << 3))] = f2bf(vv);
        }
      }
    }
    __syncthreads();
    const int c0 = (tid & 15) * 8;
    #pragma unroll
    for (int i = 0; i < 8; ++i) {
      const int gr = (tid >> 4) + i * 16;
      uint4 v4 = *(const uint4*)&LB[gr * 128 + (c0 ^ ((gr & 7) << 3))];
      *(uint4*)(Cd + (bm + gr) * Nt + cl0 + c0) = v4;
    }
    return;
  }

  if (mode == 4) {
    #pragma unroll
    for (int nf = 0; nf < 4; ++nf) {
      const int cl = bn - 1536 + wn * 64 + nf * 16 + lr;
      const int hcol = cl >> 6, dcol = cl & 63;
      const float bvv = bias[1536 + cl];
      #pragma unroll
      for (int mf = 0; mf < 4; ++mf) {
        const long t0 = bm + wm * 64 + mf * 16 + r0;
        const int bb2 = (int)(t0 >> 12), s0 = (int)(t0 & (S - 1));
        const float v0 = acc[mf][nf][0] + bvv, v1 = acc[mf][nf][1] + bvv;
        const float v2 = acc[mf][nf][2] + bvv, v3 = acc[mf][nf][3] + bvv;
        *(uint2*)(Cu + 2 * HD + (((long)bb2 * H + hcol) * 64 + dcol) * S + s0) =
            make_uint2(pack2(v0, v1), pack2(v2, v3));
      }
    }
    return;
  }

  #pragma unroll
  for (int nf = 0; nf < 4; ++nf) {
    const int col = bn + wn * 64 + nf * 16 + lr;
    const float bvv = addb ? bias[col] : 0.f;
    #pragma unroll
    for (int mf = 0; mf < 4; ++mf) {
      #pragma unroll
      for (int r = 0; r < 4; ++r) {
        const long row = bm + wm * 64 + mf * 16 + r0 + r;
        float vv = acc[mf][nf][r] + bvv;
        if (mode == 2) {
          if (ksplit > 1) atomicAdd(&Cf[row * N + col], vv);
          else            Cf[row * N + col] += vv;
        } else {
          Cf[row * N + col] = vv;
        }
      }
    }
  }
}

// ---------------- MFMA block attention: swapped QK^T, defer-max, MFMA l-sum ---------
// 1D grid 1680 = B*H*70; XCD-chunked bijective remap (1680 = 8*210).
// Mask for tile jj+1 prefetched during tile jj (drains with STAGE under vmcnt(4)).
__global__ __launch_bounds__(256) void mattn_kern(
    const u16* __restrict__ q, const u16* __restrict__ k, const u16* __restrict__ vt,
    const float* __restrict__ mask, const int* __restrict__ rb,
    u16* __restrict__ ctx, float* __restrict__ part)
{
  int lin = blockIdx.x;
  lin = (lin & 7) * 210 + (lin >> 3);          // XCD-chunked (1680 = 8*210, bijective)
  const int x  = lin % 70;
  const int hh = (lin / 70) % H;
  const int b  = lin / 840;

  int qb, kv0, nkv, qb2 = 0, ch = 0, dense;
  if (x < 62) { dense = 0; qb = x + 1; kv0 = 0; nkv = NKV; }
  else {
    dense = 1;
    const int dx = x - 62;
    qb2 = dx >> 2; ch = dx & 3;
    qb = qb2 ? NB - 1 : 0; kv0 = ch * (NB / NCH); nkv = NB / NCH;
  }
  const int tid = threadIdx.x, lane = tid & 63, w = tid >> 6;
  const int lr = lane & 15, hi = lane >> 4;

  __shared__ u16 KV[2][8192];    // per stage: K [0..4095] (swz), V^T [4096..8191] (swz)
  __shared__ u16 Ps[64][72];     // P tile (intra-wave) / ctx transpose buffer

  const long qrow0 = (long)b * S + qb * 64;
  bf16x8 qf[2];
  {
    const u16* qp = q + (qrow0 + w * 16 + lr) * D + hh * 64 + hi * 8;
    qf[0] = *(const bf16x8*)(qp);
    qf[1] = *(const bf16x8*)(qp + 32);
  }
  const long vtbase = (((long)b * H + hh) * 64) * S;

  bf16x8 ones8;
  #pragma unroll
  for (int i = 0; i < 8; ++i) ones8[i] = __builtin_bit_cast(bf16, (u16)0x3F80);

  auto kbof = [&](int j) -> int {
    if (dense) return kv0 + j;
    if (j < 3) return qb - 1 + j;
    if (j == 3) return 0;
    if (j == 4) return NB - 1;
    return rb[qb * 3 + (j - 5)];
  };

  auto STAGE = [&](u16* st, int kb) {   // 4 gload16 per wave
    const long krow0 = (long)b * S + kb * 64;
    #pragma unroll
    for (int c = 0; c < 2; ++c) {
      const int n = (w * 2 + c) * 64 + lane;
      const int row = n >> 3;
      const int g2 = (n & 7) ^ (row & 7);
      gload16(k + (krow0 + row) * D + hh * 64 + g2 * 8, st + (w * 2 + c) * 512);
      gload16(vt + vtbase + (long)row * S + kb * 64 + g2 * 8, st + 4096 + (w * 2 + c) * 512);
    }
  };

  f32x4 acc[4];
  #pragma unroll
  for (int nf = 0; nf < 4; ++nf) acc[nf] = (f32x4){0.f, 0.f, 0.f, 0.f};
  f32x4 lacc = (f32x4){0.f, 0.f, 0.f, 0.f};      // row-sums of P (rows = hi*4+r)
  float m_run = -1e30f;                           // my q-row (w*16+lr), log2 domain

  const float C2 = SCALE * L2E;

  float4 mk4[4];
  auto LOADMASK = [&](int kb) {
    const long r = (long)b * S + kb * 64;
    #pragma unroll
    for (int kf = 0; kf < 4; ++kf)
      mk4[kf] = *(const float4*)(mask + r + kf * 16 + hi * 4);
  };

  STAGE(KV[0], kbof(0));
  LOADMASK(kbof(0));

  for (int jj = 0; jj < nkv; ++jj) {
    if (jj + 1 < nkv) {
      STAGE(KV[(jj + 1) & 1], kbof(jj + 1));
      asm volatile("s_waitcnt vmcnt(4)" ::: "memory");
    } else {
      asm volatile("s_waitcnt vmcnt(0)" ::: "memory");
    }
    __builtin_amdgcn_s_barrier();
    __builtin_amdgcn_sched_barrier(0);

    const u16* Ks = KV[jj & 1];
    const u16* Vs = Ks + 4096;

    // ---- QK^T swapped: C[key][q]; sc[kf][r] = score(key=kf*16+hi*4+r, q=w*16+lr)
    f32x4 sc[4];
    #pragma unroll
    for (int kf = 0; kf < 4; ++kf) sc[kf] = (f32x4){0.f, 0.f, 0.f, 0.f};
    __builtin_amdgcn_s_setprio(1);
    #pragma unroll
    for (int kc = 0; kc < 2; ++kc) {
      #pragma unroll
      for (int kf = 0; kf < 4; ++kf) {
        const int g2 = ((kc * 4 + hi) ^ (lr & 7)) << 3;
        bf16x8 kfr = *(const bf16x8*)&Ks[(kf * 16 + lr) * 64 + g2];
        sc[kf] = __builtin_amdgcn_mfma_f32_16x16x32_bf16(kfr, qf[kc], sc[kf], 0, 0, 0);
      }
    }
    __builtin_amdgcn_s_setprio(0);

    // ---- in-lane softmax (exp2 domain); mask preloaded (mk4)
    float sv[4][4];
    float mx = -3.0e38f;
    #pragma unroll
    for (int kf = 0; kf < 4; ++kf) {
      const float mka[4] = {mk4[kf].x, mk4[kf].y, mk4[kf].z, mk4[kf].w};
      #pragma unroll
      for (int r = 0; r < 4; ++r) {
        sv[kf][r] = sc[kf][r] * C2 + (mka[r] - 1.f) * (1e9f * L2E);
        mx = fmaxf(mx, sv[kf][r]);
      }
    }
    mx = fmaxf(mx, __shfl_xor(mx, 16));
    mx = fmaxf(mx, __shfl_xor(mx, 32));
    const bool need = mx > m_run + 8.f;
    if (__any((int)need)) {                 // T13 defer-max
      const float mn = fmaxf(m_run, mx);
      const float al = exp2f(m_run - mn);
      m_run = mn;
      #pragma unroll
      for (int r = 0; r < 4; ++r) {
        const float alr = __shfl(al, (lane & 48) | (hi * 4 + r));
        lacc[r] *= alr;
        acc[0][r] *= alr; acc[1][r] *= alr; acc[2][r] *= alr; acc[3][r] *= alr;
      }
    }
    {
      const int prow = w * 16 + lr;          // my q-row; 4 packed uint2 stores
      #pragma unroll
      for (int kf = 0; kf < 4; ++kf) {
        u32 lo = pack2(exp2f(sv[kf][0] - m_run), exp2f(sv[kf][1] - m_run));
        u32 hi2 = pack2(exp2f(sv[kf][2] - m_run), exp2f(sv[kf][3] - m_run));
        *(uint2*)&Ps[prow][kf * 16 + hi * 4] = make_uint2(lo, hi2);
      }
    }

    // ---- PV + l-sum
    __builtin_amdgcn_s_setprio(1);
    #pragma unroll
    for (int kc = 0; kc < 2; ++kc) {
      bf16x8 pf = *(const bf16x8*)&Ps[w * 16 + lr][kc * 32 + hi * 8];
      #pragma unroll
      for (int nf = 0; nf < 4; ++nf) {
        const int g2 = ((kc * 4 + hi) ^ (lr & 7)) << 3;
        bf16x8 vfr = *(const bf16x8*)&Vs[(nf * 16 + lr) * 64 + g2];
        acc[nf] = __builtin_amdgcn_mfma_f32_16x16x32_bf16(pf, vfr, acc[nf], 0, 0, 0);
      }
      lacc = __builtin_amdgcn_mfma_f32_16x16x32_bf16(pf, ones8, lacc, 0, 0, 0);
    }
    __builtin_amdgcn_s_setprio(0);

    if (jj + 1 < nkv) LOADMASK(kbof(jj + 1));   // prefetch next tile's mask

    __builtin_amdgcn_s_barrier();    // KV[jj&1] reads done; free for next iter's STAGE
  }

  if (!dense) {
    // coalesced ctx store via Ps transpose
    #pragma unroll
    for (int r = 0; r < 4; ++r) {
      const float inv = 1.f / lacc[r];
      const int prow = w * 16 + hi * 4 + r;
      Ps[prow][ 0 + lr] = f2bf(acc[0][r] * inv);
      Ps[prow][16 + lr] = f2bf(acc[1][r] * inv);
      Ps[prow][32 + lr] = f2bf(acc[2][r] * inv);
      Ps[prow][48 + lr] = f2bf(acc[3][r] * inv);
    }
    __syncthreads();
    const int r2 = tid >> 2, c2 = (tid & 3) * 16;
    uint4 v0 = *(const uint4*)&Ps[r2][c2];
    uint4 v1 = *(const uint4*)&Ps[r2][c2 + 8];
    u16* op = ctx + (qrow0 + r2) * D + hh * 64 + c2;
    *(uint4*)(op)     = v0;
    *(uint4*)(op + 8) = v1;
  } else {
    const long pb = ((((long)b * H + hh) * 2 + qb2) * NCH + ch) * (64 * 68);
    #pragma unroll
    for (int r = 0; r < 4; ++r) {
      const float m_r = __shfl(m_run, (lane & 48) | (hi * 4 + r));
      float* pp = part + pb + (w * 16 + hi * 4 + r) * 68;
      pp[ 0 + lr] = acc[0][r];
      pp[16 + lr] = acc[1][r];
      pp[32 + lr] = acc[2][r];
      pp[48 + lr] = acc[3][r];
      if (lr == 0) { pp[64] = m_r; pp[65] = lacc[r]; }  // m in log2 domain
    }
  }
}

// ---------------- combine dense split-K partials (exp2 domain) ----------------
__global__ __launch_bounds__(256) void attn_combine_kern(
    const float* __restrict__ part, u16* __restrict__ ctx)
{
  const int g = blockIdx.x;
  const int qb2 = g & 1;
  const int hh = (g >> 1) % H;
  const int b  = g / (2 * H);
  const int r  = threadIdx.x >> 2;
  const int d0 = (threadIdx.x & 3) * 16;
  const long pb = (long)g * NCH * 64 * 68;
  float mg = -1e30f;
  for (int ch = 0; ch < NCH; ++ch)
    mg = fmaxf(mg, part[pb + ch * 64 * 68 + r * 68 + 64]);
  float lg = 0.f;
  float a[16] = {};
  for (int ch = 0; ch < NCH; ++ch) {
    const float* pp = part + pb + ch * 64 * 68 + r * 68;
    const float w = exp2f(pp[64] - mg);
    lg += pp[65] * w;
    #pragma unroll
    for (int i = 0; i < 4; ++i) {
      float4 t4 = *(const float4*)(pp + d0 + i * 4);
      a[i*4+0] += t4.x * w; a[i*4+1] += t4.y * w; a[i*4+2] += t4.z * w; a[i*4+3] += t4.w * w;
    }
  }
  const int qb = qb2 ? NB - 1 : 0;
  const float inv = 1.f / lg;
  u16* op = ctx + ((long)b * S + qb * 64 + r) * D + hh * 64 + d0;
  #pragma unroll
  for (int i = 0; i < 4; ++i)
    *(uint2*)(op + i * 4) = make_uint2(pack2(a[i*4+0]*inv, a[i*4+1]*inv),
                                       pack2(a[i*4+2]*inv, a[i*4+3]*inv));
}

// ---------------- span mean-pool + head ----------------
__global__ __launch_bounds__(256) void span_head_kern(
    const float* __restrict__ h, const int* __restrict__ spans,
    const float* __restrict__ hw, const float* __restrict__ hb, float* __restrict__ out)
{
  __shared__ float s0[4], s1[4];
  const int bn = blockIdx.x;
  const int tid = threadIdx.x;
  const int st = spans[bn * 2], en = spans[bn * 2 + 1];
  const int b = bn >> 3;
  float a0 = 0.f, a1 = 0.f, a2 = 0.f;
  for (int s = st; s < en; ++s) {
    const float* row = h + ((long)b * S + s) * D;
    a0 += row[tid]; a1 += row[tid + 256]; a2 += row[tid + 512];
  }
  const float inv = 1.f / (float)(en - st);
  a0 *= inv; a1 *= inv; a2 *= inv;
  float p0 = a0 * hw[tid * 2]     + a1 * hw[(tid + 256) * 2]     + a2 * hw[(tid + 512) * 2];
  float p1 = a0 * hw[tid * 2 + 1] + a1 * hw[(tid + 256) * 2 + 1] + a2 * hw[(tid + 512) * 2 + 1];
  #pragma unroll
  for (int o = 32; o; o >>= 1) { p0 += __shfl_xor(p0, o); p1 += __shfl_xor(p1, o); }
  if ((tid & 63) == 0) { s0[tid >> 6] = p0; s1[tid >> 6] = p1; }
  __syncthreads();
  if (tid == 0) {
    out[bn * 2]     = s0[0] + s0[1] + s0[2] + s0[3] + hb[0];
    out[bn * 2 + 1] = s1[0] + s1[1] + s1[2] + s1[3] + hb[1];
  }
}

// ---------------- launcher ----------------
extern "C" void kernel_launch(void* const* d_in, const int* in_sizes, int n_in,
                              void* d_out, int out_size, void* d_ws, size_t ws_size,
                              hipStream_t stream) {
  const int*   input_ids  = (const int*)  d_in[0];
  const float* attn_mask  = (const float*)d_in[1];
  const int*   tok_type   = (const int*)  d_in[2];
  const int*   spans      = (const int*)  d_in[3];
  const int*   rand_blk   = (const int*)  d_in[4];
  const float* word_emb   = (const float*)d_in[5];
  const float* pos_emb    = (const float*)d_in[6];
  const float* type_emb   = (const float*)d_in[7];
  const float* emb_g      = (const float*)d_in[8];
  const float* emb_b      = (const float*)d_in[9];
  const float* qkv_w      = (const float*)d_in[10];
  const float* qkv_b      = (const float*)d_in[11];
  const float* aow        = (const float*)d_in[12];
  const float* aob        = (const float*)d_in[13];
  const float* ln1g       = (const float*)d_in[14];
  const float* ln1b       = (const float*)d_in[15];
  const float* ff1w       = (const float*)d_in[16];
  const float* ff1b       = (const float*)d_in[17];
  const float* ff2w       = (const float*)d_in[18];
  const float* ff2b       = (const float*)d_in[19];
  const float* ln2g       = (const float*)d_in[20];
  const float* ln2b       = (const float*)d_in[21];
  const float* headw      = (const float*)d_in[22];
  const float* headb      = (const float*)d_in[23];

  float* ws    = (float*)d_ws;
  float* h     = ws;                          // [M,D] fp32
  u16*   qkvb  = (u16*)(ws + HD);             // q,k bf16 [M,D]; vt [B,H,64,S]
  u16*   ffb   = (u16*)(ws + HD);             // [M,F] bf16 overlays qkv region
  u16*   ctx16 = (u16*)(ws + 3 * HD);         // [M,D] bf16
  u16*   hb    = (u16*)(ws + 3 * HD + HD/2);  // [M,D] bf16
  float* part  = ws + 4 * HD;                 // dense partials ~0.84M floats
  u16*   wb    = (u16*)(ws + 4 * HD + HD/4);  // bf16 weights: [qkv6][ao2][ff1x2][ff2x2]

  // ---- weight prep (bf16 transposed), z-batched across both layers: 4 launches ----
  wtrans_kern<<<dim3(24, 24, 6), dim3(256), 0, stream>>>(qkv_w, wb, D, D, DD, DD);
  wtrans_kern<<<dim3(24, 24, 2), dim3(256), 0, stream>>>(aow, wb + OFF_AO, D, D, DD, DD);
  wtrans_kern<<<dim3(96, 24, 2), dim3(256), 0, stream>>>(ff1w, wb + OFF_FF1, D, F, DF, DF);
  wtrans_kern<<<dim3(24, 96, 2), dim3(256), 0, stream>>>(ff2w, wb + OFF_FF2, F, D, DF, DF);

  embed_ln_kern<<<dim3(M / 4), dim3(256), 0, stream>>>(
      input_ids, tok_type, word_emb, pos_emb, type_emb, emb_g, emb_b, h, hb);

  for (int l = 0; l < 2; ++l) {
    // merged QKV projection (N=2304): q,k coalesced bf16; v transposed [b,h,d,S]
    mgemm_kern<<<dim3(18, 64, 1), dim3(256), 0, stream>>>(
        hb, wb + (long)l * 3 * DD, qkv_b + (long)l * 3 * D, qkvb, 2304, D, 0, 0, 0, 4, 1);
    // block attention: 1D XCD-chunked grid (sparse 62 + dense 8 per (b,h))
    mattn_kern<<<dim3(1680), dim3(256), 0, stream>>>(
        qkvb, qkvb + HD, qkvb + 2 * HD, attn_mask, rand_blk, ctx16, part);
    attn_combine_kern<<<dim3(B * H * 2), dim3(256), 0, stream>>>(part, ctx16);
    // output projection + residual into h (ksplit=1: all-resident, no atomics)
    mgemm_kern<<<dim3(6, 64, 1), dim3(256), 0, stream>>>(
        ctx16, wb + OFF_AO + (long)l * DD, aob + (long)l * D, h, D, D, 0, 0, 0, 2, 1);
    ln_kern<<<dim3(M / 4), dim3(256), 0, stream>>>(h, ln1g + (long)l * D, ln1b + (long)l * D, hb);
    // FFN
    mgemm_kern<<<dim3(24, 64, 1), dim3(256), 0, stream>>>(
        hb, wb + OFF_FF1 + (long)l * DF, ff1b + (long)l * F, ffb, F, D, 0, 0, 0, 1, 1);
    mgemm_kern<<<dim3(6, 64, 2), dim3(256), 0, stream>>>(
        ffb, wb + OFF_FF2 + (long)l * DF, ff2b + (long)l * D, h, D, F, 0, 0, 0, 2, 2);
    ln_kern<<<dim3(M / 4), dim3(256), 0, stream>>>(h, ln2g + (long)l * D, ln2b + (long)l * D, hb);
  }

  span_head_kern<<<dim3(B * NS), dim3(256), 0, stream>>>(h, spans, headw, headb, (float*)d_out);
}

// Round 21
// 618.559 us; speedup vs baseline: 1.0545x; 1.0545x over previous
//
#include <hip/hip_runtime.h>

// ---------------- constants ----------------
constexpr int B = 2, S = 4096, D = 768, H = 12, DH = 64, BLK = 64, NB = 64, NKV = 8;
constexpr int F = 3072, NS = 8, M = B * S;            // M = 8192 tokens
constexpr int NCH = 8;                                 // dense split-K chunks (nkv=8 each)
constexpr float SCALE = 0.125f;                        // 1/sqrt(64)
constexpr float L2E = 1.44269504088896f;               // log2(e)
constexpr long HD = (long)M * D;                       // 6291456 elems per [M,D] buffer

using u16 = unsigned short;
using u32 = unsigned int;
using bf16 = __bf16;
using bf16x8 = __attribute__((ext_vector_type(8))) bf16;
using f32x4 = __attribute__((ext_vector_type(4))) float;

// bf16 weight region layout (u16 counts): [qkv x6 DD][ao x2 DD][ff1 x2 DF][ff2 x2 FD]
constexpr long DD = (long)D * D;
constexpr long DF = (long)D * F;
constexpr long OFF_AO  = 6 * DD;
constexpr long OFF_FF1 = 8 * DD;
constexpr long OFF_FF2 = 8 * DD + 2 * DF;

__device__ __forceinline__ u16 f2bf(float x) {
  u32 u = __builtin_bit_cast(u32, x);
  u = (u + 0x7fffu + ((u >> 16) & 1u)) >> 16;
  return (u16)u;
}
__device__ __forceinline__ u32 pack2(float a, float b) {
  return (u32)f2bf(a) | ((u32)f2bf(b) << 16);
}
// fast tanh-gelu: 0.5x(1+tanh(u)) == x - x/(exp(2u)+1); inf-safe both tails
__device__ __forceinline__ float fast_gelu(float x) {
  float u = 0.7978845608028654f * (x + 0.044715f * x * x * x);
  float t = __expf(u + u);
  return x - x * __builtin_amdgcn_rcpf(t + 1.f);
}

// async 16B global -> LDS (dest = wave-uniform base + lane*16)
__device__ __forceinline__ void gload16(const void* g, void* l) {
  __builtin_amdgcn_global_load_lds(
      (const __attribute__((address_space(1))) u32*)g,
      (__attribute__((address_space(3))) u32*)l, 16, 0, 0);
}

// ---------------- weight transpose + cast: out[n][k] = bf16(in[k][n]) ----------------
__global__ __launch_bounds__(256) void wtrans_kern(
    const float* __restrict__ in, u16* __restrict__ out, int K, int N, long inz, long outz)
{
  in += (long)blockIdx.z * inz; out += (long)blockIdx.z * outz;
  __shared__ float T[32][33];
  const int n0 = blockIdx.x * 32, k0 = blockIdx.y * 32;
  const int c = threadIdx.x & 31, r8 = threadIdx.x >> 5;
  #pragma unroll
  for (int i = 0; i < 4; ++i)
    T[r8 + i * 8][c] = in[(long)(k0 + r8 + i * 8) * N + n0 + c];
  __syncthreads();
  #pragma unroll
  for (int i = 0; i < 4; ++i)
    out[(long)(n0 + r8 + i * 8) * K + k0 + c] = f2bf(T[c][r8 + i * 8]);
}

// ---------------- embedding + LN: wave-per-row, float4, no LDS/barrier ----------------
__global__ __launch_bounds__(256) void embed_ln_kern(
    const int* __restrict__ ids, const int* __restrict__ tt,
    const float* __restrict__ we, const float* __restrict__ pe, const float* __restrict__ te,
    const float* __restrict__ g, const float* __restrict__ bb,
    float* __restrict__ h, u16* __restrict__ hb)
{
  const long i = (long)blockIdx.x * 4 + (threadIdx.x >> 6);
  const int lane = threadIdx.x & 63;
  const int c = lane * 4;
  const int s = (int)(i & (S - 1));
  const long wo = (long)ids[i] * D;
  const long to = (long)tt[i] * D;
  const long po = (long)s * D;
  float4 x0, x1, x2;
  {
    float4 a0 = *(const float4*)(we + wo + c),       p0 = *(const float4*)(pe + po + c),
           t0 = *(const float4*)(te + to + c);
    float4 a1 = *(const float4*)(we + wo + c + 256), p1 = *(const float4*)(pe + po + c + 256),
           t1 = *(const float4*)(te + to + c + 256);
    float4 a2 = *(const float4*)(we + wo + c + 512), p2 = *(const float4*)(pe + po + c + 512),
           t2 = *(const float4*)(te + to + c + 512);
    x0 = make_float4(a0.x+p0.x+t0.x, a0.y+p0.y+t0.y, a0.z+p0.z+t0.z, a0.w+p0.w+t0.w);
    x1 = make_float4(a1.x+p1.x+t1.x, a1.y+p1.y+t1.y, a1.z+p1.z+t1.z, a1.w+p1.w+t1.w);
    x2 = make_float4(a2.x+p2.x+t2.x, a2.y+p2.y+t2.y, a2.z+p2.z+t2.z, a2.w+p2.w+t2.w);
  }
  float sm = x0.x+x0.y+x0.z+x0.w + x1.x+x1.y+x1.z+x1.w + x2.x+x2.y+x2.z+x2.w;
  float sq = x0.x*x0.x+x0.y*x0.y+x0.z*x0.z+x0.w*x0.w
           + x1.x*x1.x+x1.y*x1.y+x1.z*x1.z+x1.w*x1.w
           + x2.x*x2.x+x2.y*x2.y+x2.z*x2.z+x2.w*x2.w;
  #pragma unroll
  for (int o = 32; o; o >>= 1) { sm += __shfl_xor(sm, o); sq += __shfl_xor(sq, o); }
  const float mean = sm * (1.f / D);
  const float var  = sq * (1.f / D) - mean * mean;
  const float rs   = rsqrtf(var + 1e-12f);
  float4 g0 = *(const float4*)(g + c),  g1 = *(const float4*)(g + c + 256),
         g2 = *(const float4*)(g + c + 512);
  float4 b0 = *(const float4*)(bb + c), b1 = *(const float4*)(bb + c + 256),
         b2 = *(const float4*)(bb + c + 512);
  float* row = h + i * D;
  u16* rb = hb + i * D;
  float4 y0 = make_float4((x0.x-mean)*rs*g0.x+b0.x, (x0.y-mean)*rs*g0.y+b0.y,
                          (x0.z-mean)*rs*g0.z+b0.z, (x0.w-mean)*rs*g0.w+b0.w);
  float4 y1 = make_float4((x1.x-mean)*rs*g1.x+b1.x, (x1.y-mean)*rs*g1.y+b1.y,
                          (x1.z-mean)*rs*g1.z+b1.z, (x1.w-mean)*rs*g1.w+b1.w);
  float4 y2 = make_float4((x2.x-mean)*rs*g2.x+b2.x, (x2.y-mean)*rs*g2.y+b2.y,
                          (x2.z-mean)*rs*g2.z+b2.z, (x2.w-mean)*rs*g2.w+b2.w);
  *(float4*)(row + c)       = y0;
  *(float4*)(row + c + 256) = y1;
  *(float4*)(row + c + 512) = y2;
  *(uint2*)(rb + c)       = make_uint2(pack2(y0.x, y0.y), pack2(y0.z, y0.w));
  *(uint2*)(rb + c + 256) = make_uint2(pack2(y1.x, y1.y), pack2(y1.z, y1.w));
  *(uint2*)(rb + c + 512) = make_uint2(pack2(y2.x, y2.y), pack2(y2.z, y2.w));
}

// ---------------- LayerNorm: wave-per-row, float4, no LDS/barrier ----------------
__global__ __launch_bounds__(256) void ln_kern(
    float* __restrict__ h, const float* __restrict__ g, const float* __restrict__ bb,
    u16* __restrict__ hb)
{
  const long i = (long)blockIdx.x * 4 + (threadIdx.x >> 6);
  const int lane = threadIdx.x & 63;
  const int c = lane * 4;
  float* row = h + i * D;
  u16* rb = hb + i * D;
  float4 x0 = *(const float4*)(row + c);
  float4 x1 = *(const float4*)(row + c + 256);
  float4 x2 = *(const float4*)(row + c + 512);
  float sm = x0.x+x0.y+x0.z+x0.w + x1.x+x1.y+x1.z+x1.w + x2.x+x2.y+x2.z+x2.w;
  float sq = x0.x*x0.x+x0.y*x0.y+x0.z*x0.z+x0.w*x0.w
           + x1.x*x1.x+x1.y*x1.y+x1.z*x1.z+x1.w*x1.w
           + x2.x*x2.x+x2.y*x2.y+x2.z*x2.z+x2.w*x2.w;
  #pragma unroll
  for (int o = 32; o; o >>= 1) { sm += __shfl_xor(sm, o); sq += __shfl_xor(sq, o); }
  const float mean = sm * (1.f / D);
  const float var  = sq * (1.f / D) - mean * mean;
  const float rs   = rsqrtf(var + 1e-12f);
  float4 g0 = *(const float4*)(g + c),  g1 = *(const float4*)(g + c + 256),
         g2 = *(const float4*)(g + c + 512);
  float4 b0 = *(const float4*)(bb + c), b1 = *(const float4*)(bb + c + 256),
         b2 = *(const float4*)(bb + c + 512);
  float4 y0 = make_float4((x0.x-mean)*rs*g0.x+b0.x, (x0.y-mean)*rs*g0.y+b0.y,
                          (x0.z-mean)*rs*g0.z+b0.z, (x0.w-mean)*rs*g0.w+b0.w);
  float4 y1 = make_float4((x1.x-mean)*rs*g1.x+b1.x, (x1.y-mean)*rs*g1.y+b1.y,
                          (x1.z-mean)*rs*g1.z+b1.z, (x1.w-mean)*rs*g1.w+b1.w);
  float4 y2 = make_float4((x2.x-mean)*rs*g2.x+b2.x, (x2.y-mean)*rs*g2.y+b2.y,
                          (x2.z-mean)*rs*g2.z+b2.z, (x2.w-mean)*rs*g2.w+b2.w);
  *(float4*)(row + c)       = y0;
  *(float4*)(row + c + 256) = y1;
  *(float4*)(row + c + 512) = y2;
  *(uint2*)(rb + c)       = make_uint2(pack2(y0.x, y0.y), pack2(y0.z, y0.w));
  *(uint2*)(rb + c + 256) = make_uint2(pack2(y1.x, y1.y), pack2(y1.z, y1.w));
  *(uint2*)(rb + c + 512) = make_uint2(pack2(y2.x, y2.y), pack2(y2.z, y2.w));
}

// ---------------- bf16 MFMA GEMM: BK=64, 2-stage, counted vmcnt + raw barriers ------
// (round-10 core, best known)
__global__ __launch_bounds__(256) void mgemm_kern(
    const u16* __restrict__ A, const u16* __restrict__ Wt,
    const float* __restrict__ bias, void* __restrict__ Cv,
    int N, int K, long wz, long bz, long cz, int mode, int ksplit)
{
  const int z = blockIdx.z;
  int k0 = 0, kend = K;
  if (ksplit > 1) {
    const int kch = K / ksplit;
    k0 = z * kch; kend = k0 + kch;
  } else {
    Wt += (long)z * wz; bias += (long)z * bz;
  }
  const int gx = gridDim.x;
  const int nwg = gx * gridDim.y;
  int bid = blockIdx.y * gx + blockIdx.x;
  bid = (bid & 7) * (nwg >> 3) + (bid >> 3);
  const long bm = (long)(bid / gx) * 128;
  const int bn = (bid % gx) * 128;

  const int tid = threadIdx.x;
  const int lane = tid & 63, w = tid >> 6;
  const int wm = w >> 1, wn = w & 1;
  const int ls = lane >> 4, lr = lane & 15;

  __shared__ u16 LB[32768];
  u16* const St0 = LB;
  u16* const St1 = LB + 16384;

  f32x4 acc[4][4];
  #pragma unroll
  for (int i = 0; i < 4; ++i)
    #pragma unroll
    for (int j = 0; j < 4; ++j)
      acc[i][j] = (f32x4){0.f, 0.f, 0.f, 0.f};

  auto STAGE = [&](u16* buf, int kk) {
    #pragma unroll
    for (int c = 0; c < 4; ++c) {
      const int n = (w * 4 + c) * 64 + lane;
      const int row = n >> 3;
      const int kc2 = (n & 7) ^ (row & 7);
      gload16(A  + (bm + row) * K + kk + kc2 * 8, buf + (w * 4 + c) * 512);
      gload16(Wt + (long)(bn + row) * K + kk + kc2 * 8, buf + 8192 + (w * 4 + c) * 512);
    }
  };

  STAGE(St0, k0);
  int cur = 0;
  for (int kk = k0; kk < kend; kk += 64) {
    if (kk + 64 < kend) {
      STAGE(cur ? St0 : St1, kk + 64);
      asm volatile("s_waitcnt vmcnt(8)" ::: "memory");
    } else {
      asm volatile("s_waitcnt vmcnt(0)" ::: "memory");
    }
    __builtin_amdgcn_s_barrier();
    __builtin_amdgcn_sched_barrier(0);
    const u16* AsL = cur ? St1 : St0;
    const u16* BsL = AsL + 8192;
    __builtin_amdgcn_s_setprio(1);
    #pragma unroll
    for (int ks = 0; ks < 2; ++ks) {
      bf16x8 af[4], bv[4];
      const int kc = ks * 4 + ls;
      const int sw = (kc ^ (lr & 7)) << 3;
      #pragma unroll
      for (int mf = 0; mf < 4; ++mf)
        af[mf] = *(const bf16x8*)&AsL[(wm * 64 + mf * 16 + lr) * 64 + sw];
      #pragma unroll
      for (int nf = 0; nf < 4; ++nf)
        bv[nf] = *(const bf16x8*)&BsL[(wn * 64 + nf * 16 + lr) * 64 + sw];
      #pragma unroll
      for (int mf = 0; mf < 4; ++mf)
        #pragma unroll
        for (int nf = 0; nf < 4; ++nf)
          acc[mf][nf] = __builtin_amdgcn_mfma_f32_16x16x32_bf16(
              af[mf], bv[nf], acc[mf][nf], 0, 0, 0);
    }
    __builtin_amdgcn_s_setprio(0);
    __builtin_amdgcn_s_barrier();
    cur ^= 1;
  }

  float* Cf = (float*)Cv + (long)z * cz;
  u16*   Cu = (u16*)Cv  + (long)z * cz;
  const int r0 = ls * 4;
  const bool addb = (ksplit == 1) || (z == 0);

  if (mode == 1 || (mode == 4 && bn < 1536)) {
    const int t = (mode == 4) ? (bn / 768) : 0;
    const int cl0 = (mode == 4) ? (bn - t * 768) : bn;
    const int Nt = (mode == 4) ? 768 : N;
    u16* Cd = (mode == 4) ? (Cu + (long)t * HD) : Cu;
    #pragma unroll
    for (int nf = 0; nf < 4; ++nf) {
      const int col = wn * 64 + nf * 16 + lr;
      const float bvv = bias[bn + col];
      #pragma unroll
      for (int mf = 0; mf < 4; ++mf) {
        #pragma unroll
        for (int r = 0; r < 4; ++r) {
          const int rowl = wm * 64 + mf * 16 + r0 + r;
          float vv = acc[mf][nf][r] + bvv;
          if (mode == 1) vv = fast_gelu(vv);
          LB[rowl * 128 + (col ^ ((rowl & 7) << 3))] = f2bf(vv);
        }
      }
    }
    __syncthreads();
    const int c0 = (tid & 15) * 8;
    #pragma unroll
    for (int i = 0; i < 8; ++i) {
      const int gr = (tid >> 4) + i * 16;
      uint4 v4 = *(const uint4*)&LB[gr * 128 + (c0 ^ ((gr & 7) << 3))];
      *(uint4*)(Cd + (bm + gr) * Nt + cl0 + c0) = v4;
    }
    return;
  }

  if (mode == 4) {
    #pragma unroll
    for (int nf = 0; nf < 4; ++nf) {
      const int cl = bn - 1536 + wn * 64 + nf * 16 + lr;
      const int hcol = cl >> 6, dcol = cl & 63;
      const float bvv = bias[1536 + cl];
      #pragma unroll
      for (int mf = 0; mf < 4; ++mf) {
        const long t0 = bm + wm * 64 + mf * 16 + r0;
        const int bb2 = (int)(t0 >> 12), s0 = (int)(t0 & (S - 1));
        const float v0 = acc[mf][nf][0] + bvv, v1 = acc[mf][nf][1] + bvv;
        const float v2 = acc[mf][nf][2] + bvv, v3 = acc[mf][nf][3] + bvv;
        *(uint2*)(Cu + 2 * HD + (((long)bb2 * H + hcol) * 64 + dcol) * S + s0) =
            make_uint2(pack2(v0, v1), pack2(v2, v3));
      }
    }
    return;
  }

  #pragma unroll
  for (int nf = 0; nf < 4; ++nf) {
    const int col = bn + wn * 64 + nf * 16 + lr;
    const float bvv = addb ? bias[col] : 0.f;
    #pragma unroll
    for (int mf = 0; mf < 4; ++mf) {
      #pragma unroll
      for (int r = 0; r < 4; ++r) {
        const long row = bm + wm * 64 + mf * 16 + r0 + r;
        float vv = acc[mf][nf][r] + bvv;
        if (mode == 2) {
          if (ksplit > 1) atomicAdd(&Cf[row * N + col], vv);
          else            Cf[row * N + col] += vv;
        } else {
          Cf[row * N + col] = vv;
        }
      }
    }
  }
}

// ---------------- MFMA block attention: swapped QK^T, defer-max, MFMA l-sum ---------
// 1D grid 1872 = B*H*78; XCD-chunked bijective remap (1872 = 8*234).
// Dense split into 8 chunks (nkv=8) so every block does exactly 8 KV tiles.
__global__ __launch_bounds__(256) void mattn_kern(
    const u16* __restrict__ q, const u16* __restrict__ k, const u16* __restrict__ vt,
    const float* __restrict__ mask, const int* __restrict__ rb,
    u16* __restrict__ ctx, float* __restrict__ part)
{
  int lin = blockIdx.x;
  lin = (lin & 7) * 234 + (lin >> 3);          // XCD-chunked (1872 = 8*234, bijective)
  const int x  = lin % 78;
  const int hh = (lin / 78) % H;
  const int b  = lin / 936;

  int qb, kv0, nkv, qb2 = 0, ch = 0, dense;
  if (x < 62) { dense = 0; qb = x + 1; kv0 = 0; nkv = NKV; }
  else {
    dense = 1;
    const int dx = x - 62;                      // 0..15
    qb2 = dx >> 3; ch = dx & 7;
    qb = qb2 ? NB - 1 : 0; kv0 = ch * (NB / NCH); nkv = NB / NCH;   // 8 tiles
  }
  const int tid = threadIdx.x, lane = tid & 63, w = tid >> 6;
  const int lr = lane & 15, hi = lane >> 4;

  __shared__ u16 KV[2][8192];    // per stage: K [0..4095] (swz), V^T [4096..8191] (swz)
  __shared__ u16 Ps[64][72];     // P tile (intra-wave) / ctx transpose buffer

  const long qrow0 = (long)b * S + qb * 64;
  bf16x8 qf[2];
  {
    const u16* qp = q + (qrow0 + w * 16 + lr) * D + hh * 64 + hi * 8;
    qf[0] = *(const bf16x8*)(qp);
    qf[1] = *(const bf16x8*)(qp + 32);
  }
  const long vtbase = (((long)b * H + hh) * 64) * S;

  bf16x8 ones8;
  #pragma unroll
  for (int i = 0; i < 8; ++i) ones8[i] = __builtin_bit_cast(bf16, (u16)0x3F80);

  auto kbof = [&](int j) -> int {
    if (dense) return kv0 + j;
    if (j < 3) return qb - 1 + j;
    if (j == 3) return 0;
    if (j == 4) return NB - 1;
    return rb[qb * 3 + (j - 5)];
  };

  auto STAGE = [&](u16* st, int kb) {   // 4 gload16 per wave
    const long krow0 = (long)b * S + kb * 64;
    #pragma unroll
    for (int c = 0; c < 2; ++c) {
      const int n = (w * 2 + c) * 64 + lane;
      const int row = n >> 3;
      const int g2 = (n & 7) ^ (row & 7);
      gload16(k + (krow0 + row) * D + hh * 64 + g2 * 8, st + (w * 2 + c) * 512);
      gload16(vt + vtbase + (long)row * S + kb * 64 + g2 * 8, st + 4096 + (w * 2 + c) * 512);
    }
  };

  f32x4 acc[4];
  #pragma unroll
  for (int nf = 0; nf < 4; ++nf) acc[nf] = (f32x4){0.f, 0.f, 0.f, 0.f};
  f32x4 lacc = (f32x4){0.f, 0.f, 0.f, 0.f};      // row-sums of P (rows = hi*4+r)
  float m_run = -1e30f;                           // my q-row (w*16+lr), log2 domain

  const float C2 = SCALE * L2E;

  float4 mk4[4];
  auto LOADMASK = [&](int kb) {
    const long r = (long)b * S + kb * 64;
    #pragma unroll
    for (int kf = 0; kf < 4; ++kf)
      mk4[kf] = *(const float4*)(mask + r + kf * 16 + hi * 4);
  };

  STAGE(KV[0], kbof(0));
  LOADMASK(kbof(0));

  for (int jj = 0; jj < nkv; ++jj) {
    if (jj + 1 < nkv) {
      STAGE(KV[(jj + 1) & 1], kbof(jj + 1));
      asm volatile("s_waitcnt vmcnt(4)" ::: "memory");
    } else {
      asm volatile("s_waitcnt vmcnt(0)" ::: "memory");
    }
    __builtin_amdgcn_s_barrier();
    __builtin_amdgcn_sched_barrier(0);

    const u16* Ks = KV[jj & 1];
    const u16* Vs = Ks + 4096;

    // ---- QK^T swapped: C[key][q]; sc[kf][r] = score(key=kf*16+hi*4+r, q=w*16+lr)
    f32x4 sc[4];
    #pragma unroll
    for (int kf = 0; kf < 4; ++kf) sc[kf] = (f32x4){0.f, 0.f, 0.f, 0.f};
    __builtin_amdgcn_s_setprio(1);
    #pragma unroll
    for (int kc = 0; kc < 2; ++kc) {
      #pragma unroll
      for (int kf = 0; kf < 4; ++kf) {
        const int g2 = ((kc * 4 + hi) ^ (lr & 7)) << 3;
        bf16x8 kfr = *(const bf16x8*)&Ks[(kf * 16 + lr) * 64 + g2];
        sc[kf] = __builtin_amdgcn_mfma_f32_16x16x32_bf16(kfr, qf[kc], sc[kf], 0, 0, 0);
      }
    }
    __builtin_amdgcn_s_setprio(0);

    // ---- in-lane softmax (exp2 domain); mask preloaded (mk4)
    float sv[4][4];
    float mx = -3.0e38f;
    #pragma unroll
    for (int kf = 0; kf < 4; ++kf) {
      const float mka[4] = {mk4[kf].x, mk4[kf].y, mk4[kf].z, mk4[kf].w};
      #pragma unroll
      for (int r = 0; r < 4; ++r) {
        sv[kf][r] = sc[kf][r] * C2 + (mka[r] - 1.f) * (1e9f * L2E);
        mx = fmaxf(mx, sv[kf][r]);
      }
    }
    mx = fmaxf(mx, __shfl_xor(mx, 16));
    mx = fmaxf(mx, __shfl_xor(mx, 32));
    const bool need = mx > m_run + 8.f;
    if (__any((int)need)) {                 // T13 defer-max
      const float mn = fmaxf(m_run, mx);
      const float al = exp2f(m_run - mn);
      m_run = mn;
      #pragma unroll
      for (int r = 0; r < 4; ++r) {
        const float alr = __shfl(al, (lane & 48) | (hi * 4 + r));
        lacc[r] *= alr;
        acc[0][r] *= alr; acc[1][r] *= alr; acc[2][r] *= alr; acc[3][r] *= alr;
      }
    }
    {
      const int prow = w * 16 + lr;          // my q-row; 4 packed uint2 stores
      #pragma unroll
      for (int kf = 0; kf < 4; ++kf) {
        u32 lo = pack2(exp2f(sv[kf][0] - m_run), exp2f(sv[kf][1] - m_run));
        u32 hi2 = pack2(exp2f(sv[kf][2] - m_run), exp2f(sv[kf][3] - m_run));
        *(uint2*)&Ps[prow][kf * 16 + hi * 4] = make_uint2(lo, hi2);
      }
    }

    // ---- PV + l-sum
    __builtin_amdgcn_s_setprio(1);
    #pragma unroll
    for (int kc = 0; kc < 2; ++kc) {
      bf16x8 pf = *(const bf16x8*)&Ps[w * 16 + lr][kc * 32 + hi * 8];
      #pragma unroll
      for (int nf = 0; nf < 4; ++nf) {
        const int g2 = ((kc * 4 + hi) ^ (lr & 7)) << 3;
        bf16x8 vfr = *(const bf16x8*)&Vs[(nf * 16 + lr) * 64 + g2];
        acc[nf] = __builtin_amdgcn_mfma_f32_16x16x32_bf16(pf, vfr, acc[nf], 0, 0, 0);
      }
      lacc = __builtin_amdgcn_mfma_f32_16x16x32_bf16(pf, ones8, lacc, 0, 0, 0);
    }
    __builtin_amdgcn_s_setprio(0);

    if (jj + 1 < nkv) LOADMASK(kbof(jj + 1));   // prefetch next tile's mask

    __builtin_amdgcn_s_barrier();    // KV[jj&1] reads done; free for next iter's STAGE
  }

  if (!dense) {
    // coalesced ctx store via Ps transpose
    #pragma unroll
    for (int r = 0; r < 4; ++r) {
      const float inv = 1.f / lacc[r];
      const int prow = w * 16 + hi * 4 + r;
      Ps[prow][ 0 + lr] = f2bf(acc[0][r] * inv);
      Ps[prow][16 + lr] = f2bf(acc[1][r] * inv);
      Ps[prow][32 + lr] = f2bf(acc[2][r] * inv);
      Ps[prow][48 + lr] = f2bf(acc[3][r] * inv);
    }
    __syncthreads();
    const int r2 = tid >> 2, c2 = (tid & 3) * 16;
    uint4 v0 = *(const uint4*)&Ps[r2][c2];
    uint4 v1 = *(const uint4*)&Ps[r2][c2 + 8];
    u16* op = ctx + (qrow0 + r2) * D + hh * 64 + c2;
    *(uint4*)(op)     = v0;
    *(uint4*)(op + 8) = v1;
  } else {
    const long pb = ((((long)b * H + hh) * 2 + qb2) * NCH + ch) * (64 * 68);
    #pragma unroll
    for (int r = 0; r < 4; ++r) {
      const float m_r = __shfl(m_run, (lane & 48) | (hi * 4 + r));
      float* pp = part + pb + (w * 16 + hi * 4 + r) * 68;
      pp[ 0 + lr] = acc[0][r];
      pp[16 + lr] = acc[1][r];
      pp[32 + lr] = acc[2][r];
      pp[48 + lr] = acc[3][r];
      if (lr == 0) { pp[64] = m_r; pp[65] = lacc[r]; }  // m in log2 domain
    }
  }
}

// ---------------- combine dense split-K partials (exp2 domain) ----------------
__global__ __launch_bounds__(256) void attn_combine_kern(
    const float* __restrict__ part, u16* __restrict__ ctx)
{
  const int g = blockIdx.x;
  const int qb2 = g & 1;
  const int hh = (g >> 1) % H;
  const int b  = g / (2 * H);
  const int r  = threadIdx.x >> 2;
  const int d0 = (threadIdx.x & 3) * 16;
  const long pb = (long)g * NCH * 64 * 68;
  float mg = -1e30f;
  for (int ch = 0; ch < NCH; ++ch)
    mg = fmaxf(mg, part[pb + ch * 64 * 68 + r * 68 + 64]);
  float lg = 0.f;
  float a[16] = {};
  for (int ch = 0; ch < NCH; ++ch) {
    const float* pp = part + pb + ch * 64 * 68 + r * 68;
    const float w = exp2f(pp[64] - mg);
    lg += pp[65] * w;
    #pragma unroll
    for (int i = 0; i < 4; ++i) {
      float4 t4 = *(const float4*)(pp + d0 + i * 4);
      a[i*4+0] += t4.x * w; a[i*4+1] += t4.y * w; a[i*4+2] += t4.z * w; a[i*4+3] += t4.w * w;
    }
  }
  const int qb = qb2 ? NB - 1 : 0;
  const float inv = 1.f / lg;
  u16* op = ctx + ((long)b * S + qb * 64 + r) * D + hh * 64 + d0;
  #pragma unroll
  for (int i = 0; i < 4; ++i)
    *(uint2*)(op + i * 4) = make_uint2(pack2(a[i*4+0]*inv, a[i*4+1]*inv),
                                       pack2(a[i*4+2]*inv, a[i*4+3]*inv));
}

// ---------------- span mean-pool + head ----------------
__global__ __launch_bounds__(256) void span_head_kern(
    const float* __restrict__ h, const int* __restrict__ spans,
    const float* __restrict__ hw, const float* __restrict__ hb, float* __restrict__ out)
{
  __shared__ float s0[4], s1[4];
  const int bn = blockIdx.x;
  const int tid = threadIdx.x;
  const int st = spans[bn * 2], en = spans[bn * 2 + 1];
  const int b = bn >> 3;
  float a0 = 0.f, a1 = 0.f, a2 = 0.f;
  for (int s = st; s < en; ++s) {
    const float* row = h + ((long)b * S + s) * D;
    a0 += row[tid]; a1 += row[tid + 256]; a2 += row[tid + 512];
  }
  const float inv = 1.f / (float)(en - st);
  a0 *= inv; a1 *= inv; a2 *= inv;
  float p0 = a0 * hw[tid * 2]     + a1 * hw[(tid + 256) * 2]     + a2 * hw[(tid + 512) * 2];
  float p1 = a0 * hw[tid * 2 + 1] + a1 * hw[(tid + 256) * 2 + 1] + a2 * hw[(tid + 512) * 2 + 1];
  #pragma unroll
  for (int o = 32; o; o >>= 1) { p0 += __shfl_xor(p0, o); p1 += __shfl_xor(p1, o); }
  if ((tid & 63) == 0) { s0[tid >> 6] = p0; s1[tid >> 6] = p1; }
  __syncthreads();
  if (tid == 0) {
    out[bn * 2]     = s0[0] + s0[1] + s0[2] + s0[3] + hb[0];
    out[bn * 2 + 1] = s1[0] + s1[1] + s1[2] + s1[3] + hb[1];
  }
}

// ---------------- launcher ----------------
extern "C" void kernel_launch(void* const* d_in, const int* in_sizes, int n_in,
                              void* d_out, int out_size, void* d_ws, size_t ws_size,
                              hipStream_t stream) {
  const int*   input_ids  = (const int*)  d_in[0];
  const float* attn_mask  = (const float*)d_in[1];
  const int*   tok_type   = (const int*)  d_in[2];
  const int*   spans      = (const int*)  d_in[3];
  const int*   rand_blk   = (const int*)  d_in[4];
  const float* word_emb   = (const float*)d_in[5];
  const float* pos_emb    = (const float*)d_in[6];
  const float* type_emb   = (const float*)d_in[7];
  const float* emb_g      = (const float*)d_in[8];
  const float* emb_b      = (const float*)d_in[9];
  const float* qkv_w      = (const float*)d_in[10];
  const float* qkv_b      = (const float*)d_in[11];
  const float* aow        = (const float*)d_in[12];
  const float* aob        = (const float*)d_in[13];
  const float* ln1g       = (const float*)d_in[14];
  const float* ln1b       = (const float*)d_in[15];
  const float* ff1w       = (const float*)d_in[16];
  const float* ff1b       = (const float*)d_in[17];
  const float* ff2w       = (const float*)d_in[18];
  const float* ff2b       = (const float*)d_in[19];
  const float* ln2g       = (const float*)d_in[20];
  const float* ln2b       = (const float*)d_in[21];
  const float* headw      = (const float*)d_in[22];
  const float* headb      = (const float*)d_in[23];

  float* ws    = (float*)d_ws;
  float* h     = ws;                          // [M,D] fp32
  u16*   qkvb  = (u16*)(ws + HD);             // q,k bf16 [M,D]; vt [B,H,64,S]
  u16*   ffb   = (u16*)(ws + HD);             // [M,F] bf16 overlays qkv region
  u16*   ctx16 = (u16*)(ws + 3 * HD);         // [M,D] bf16
  u16*   hb    = (u16*)(ws + 3 * HD + HD/2);  // [M,D] bf16
  float* part  = ws + 4 * HD;                 // dense partials: 2*12*2*8*64*68 ~1.67M floats
  u16*   wb    = (u16*)(ws + 4 * HD + HD/2);  // bf16 weights: [qkv6][ao2][ff1x2][ff2x2]

  // ---- weight prep (bf16 transposed), z-batched across both layers: 4 launches ----
  wtrans_kern<<<dim3(24, 24, 6), dim3(256), 0, stream>>>(qkv_w, wb, D, D, DD, DD);
  wtrans_kern<<<dim3(24, 24, 2), dim3(256), 0, stream>>>(aow, wb + OFF_AO, D, D, DD, DD);
  wtrans_kern<<<dim3(96, 24, 2), dim3(256), 0, stream>>>(ff1w, wb + OFF_FF1, D, F, DF, DF);
  wtrans_kern<<<dim3(24, 96, 2), dim3(256), 0, stream>>>(ff2w, wb + OFF_FF2, F, D, DF, DF);

  embed_ln_kern<<<dim3(M / 4), dim3(256), 0, stream>>>(
      input_ids, tok_type, word_emb, pos_emb, type_emb, emb_g, emb_b, h, hb);

  for (int l = 0; l < 2; ++l) {
    // merged QKV projection (N=2304): q,k coalesced bf16; v transposed [b,h,d,S]
    mgemm_kern<<<dim3(18, 64, 1), dim3(256), 0, stream>>>(
        hb, wb + (long)l * 3 * DD, qkv_b + (long)l * 3 * D, qkvb, 2304, D, 0, 0, 0, 4, 1);
    // block attention: 1D XCD-chunked grid (sparse 62 + dense 16 per (b,h), 8 tiles each)
    mattn_kern<<<dim3(1872), dim3(256), 0, stream>>>(
        qkvb, qkvb + HD, qkvb + 2 * HD, attn_mask, rand_blk, ctx16, part);
    attn_combine_kern<<<dim3(B * H * 2), dim3(256), 0, stream>>>(part, ctx16);
    // output projection + residual into h (ksplit=1: all-resident, no atomics)
    mgemm_kern<<<dim3(6, 64, 1), dim3(256), 0, stream>>>(
        ctx16, wb + OFF_AO + (long)l * DD, aob + (long)l * D, h, D, D, 0, 0, 0, 2, 1);
    ln_kern<<<dim3(M / 4), dim3(256), 0, stream>>>(h, ln1g + (long)l * D, ln1b + (long)l * D, hb);
    // FFN
    mgemm_kern<<<dim3(24, 64, 1), dim3(256), 0, stream>>>(
        hb, wb + OFF_FF1 + (long)l * DF, ff1b + (long)l * F, ffb, F, D, 0, 0, 0, 1, 1);
    mgemm_kern<<<dim3(6, 64, 1), dim3(256), 0, stream>>>(
        ffb, wb + OFF_FF2 + (long)l * DF, ff2b + (long)l * D, h, D, F, 0, 0, 0, 2, 1);
    ln_kern<<<dim3(M / 4), dim3(256), 0, stream>>>(h, ln2g + (long)l * D, ln2b + (long)l * D, hb);
  }

  span_head_kern<<<dim3(B * NS), dim3(256), 0, stream>>>(h, spans, headw, headb, (float*)d_out);
}

// Round 22
// 615.878 us; speedup vs baseline: 1.0591x; 1.0044x over previous
//
#include <hip/hip_runtime.h>

// ---------------- constants ----------------
constexpr int B = 2, S = 4096, D = 768, H = 12, DH = 64, BLK = 64, NB = 64, NKV = 8;
constexpr int F = 3072, NS = 8, M = B * S;            // M = 8192 tokens
constexpr int NCH = 8;                                 // dense split-K chunks (nkv=8 each)
constexpr float SCALE = 0.125f;                        // 1/sqrt(64)
constexpr float L2E = 1.44269504088896f;               // log2(e)
constexpr long HD = (long)M * D;                       // 6291456 elems per [M,D] buffer

using u16 = unsigned short;
using u32 = unsigned int;
using bf16 = __bf16;
using bf16x8 = __attribute__((ext_vector_type(8))) bf16;
using f32x4 = __attribute__((ext_vector_type(4))) float;

// bf16 weight region layout (u16 counts): [qkv x6 DD][ao x2 DD][ff1 x2 DF][ff2 x2 FD]
constexpr long DD = (long)D * D;
constexpr long DF = (long)D * F;
constexpr long OFF_AO  = 6 * DD;
constexpr long OFF_FF1 = 8 * DD;
constexpr long OFF_FF2 = 8 * DD + 2 * DF;

__device__ __forceinline__ u16 f2bf(float x) {
  u32 u = __builtin_bit_cast(u32, x);
  u = (u + 0x7fffu + ((u >> 16) & 1u)) >> 16;
  return (u16)u;
}
__device__ __forceinline__ u32 pack2(float a, float b) {
  return (u32)f2bf(a) | ((u32)f2bf(b) << 16);
}
// fast tanh-gelu: 0.5x(1+tanh(u)) == x - x/(exp(2u)+1); inf-safe both tails
__device__ __forceinline__ float fast_gelu(float x) {
  float u = 0.7978845608028654f * (x + 0.044715f * x * x * x);
  float t = __expf(u + u);
  return x - x * __builtin_amdgcn_rcpf(t + 1.f);
}

// async 16B global -> LDS (dest = wave-uniform base + lane*16)
__device__ __forceinline__ void gload16(const void* g, void* l) {
  __builtin_amdgcn_global_load_lds(
      (const __attribute__((address_space(1))) u32*)g,
      (__attribute__((address_space(3))) u32*)l, 16, 0, 0);
}

// ---------------- weight transpose + cast: out[n][k] = bf16(in[k][n]) ----------------
__global__ __launch_bounds__(256) void wtrans_kern(
    const float* __restrict__ in, u16* __restrict__ out, int K, int N, long inz, long outz)
{
  in += (long)blockIdx.z * inz; out += (long)blockIdx.z * outz;
  __shared__ float T[32][33];
  const int n0 = blockIdx.x * 32, k0 = blockIdx.y * 32;
  const int c = threadIdx.x & 31, r8 = threadIdx.x >> 5;
  #pragma unroll
  for (int i = 0; i < 4; ++i)
    T[r8 + i * 8][c] = in[(long)(k0 + r8 + i * 8) * N + n0 + c];
  __syncthreads();
  #pragma unroll
  for (int i = 0; i < 4; ++i)
    out[(long)(n0 + r8 + i * 8) * K + k0 + c] = f2bf(T[c][r8 + i * 8]);
}

// ---------------- embedding + LN: wave-per-row, float4, no LDS/barrier ----------------
__global__ __launch_bounds__(256) void embed_ln_kern(
    const int* __restrict__ ids, const int* __restrict__ tt,
    const float* __restrict__ we, const float* __restrict__ pe, const float* __restrict__ te,
    const float* __restrict__ g, const float* __restrict__ bb,
    float* __restrict__ h, u16* __restrict__ hb)
{
  const long i = (long)blockIdx.x * 4 + (threadIdx.x >> 6);
  const int lane = threadIdx.x & 63;
  const int c = lane * 4;
  const int s = (int)(i & (S - 1));
  const long wo = (long)ids[i] * D;
  const long to = (long)tt[i] * D;
  const long po = (long)s * D;
  float4 x0, x1, x2;
  {
    float4 a0 = *(const float4*)(we + wo + c),       p0 = *(const float4*)(pe + po + c),
           t0 = *(const float4*)(te + to + c);
    float4 a1 = *(const float4*)(we + wo + c + 256), p1 = *(const float4*)(pe + po + c + 256),
           t1 = *(const float4*)(te + to + c + 256);
    float4 a2 = *(const float4*)(we + wo + c + 512), p2 = *(const float4*)(pe + po + c + 512),
           t2 = *(const float4*)(te + to + c + 512);
    x0 = make_float4(a0.x+p0.x+t0.x, a0.y+p0.y+t0.y, a0.z+p0.z+t0.z, a0.w+p0.w+t0.w);
    x1 = make_float4(a1.x+p1.x+t1.x, a1.y+p1.y+t1.y, a1.z+p1.z+t1.z, a1.w+p1.w+t1.w);
    x2 = make_float4(a2.x+p2.x+t2.x, a2.y+p2.y+t2.y, a2.z+p2.z+t2.z, a2.w+p2.w+t2.w);
  }
  float sm = x0.x+x0.y+x0.z+x0.w + x1.x+x1.y+x1.z+x1.w + x2.x+x2.y+x2.z+x2.w;
  float sq = x0.x*x0.x+x0.y*x0.y+x0.z*x0.z+x0.w*x0.w
           + x1.x*x1.x+x1.y*x1.y+x1.z*x1.z+x1.w*x1.w
           + x2.x*x2.x+x2.y*x2.y+x2.z*x2.z+x2.w*x2.w;
  #pragma unroll
  for (int o = 32; o; o >>= 1) { sm += __shfl_xor(sm, o); sq += __shfl_xor(sq, o); }
  const float mean = sm * (1.f / D);
  const float var  = sq * (1.f / D) - mean * mean;
  const float rs   = rsqrtf(var + 1e-12f);
  float4 g0 = *(const float4*)(g + c),  g1 = *(const float4*)(g + c + 256),
         g2 = *(const float4*)(g + c + 512);
  float4 b0 = *(const float4*)(bb + c), b1 = *(const float4*)(bb + c + 256),
         b2 = *(const float4*)(bb + c + 512);
  float* row = h + i * D;
  u16* rb = hb + i * D;
  float4 y0 = make_float4((x0.x-mean)*rs*g0.x+b0.x, (x0.y-mean)*rs*g0.y+b0.y,
                          (x0.z-mean)*rs*g0.z+b0.z, (x0.w-mean)*rs*g0.w+b0.w);
  float4 y1 = make_float4((x1.x-mean)*rs*g1.x+b1.x, (x1.y-mean)*rs*g1.y+b1.y,
                          (x1.z-mean)*rs*g1.z+b1.z, (x1.w-mean)*rs*g1.w+b1.w);
  float4 y2 = make_float4((x2.x-mean)*rs*g2.x+b2.x, (x2.y-mean)*rs*g2.y+b2.y,
                          (x2.z-mean)*rs*g2.z+b2.z, (x2.w-mean)*rs*g2.w+b2.w);
  *(float4*)(row + c)       = y0;
  *(float4*)(row + c + 256) = y1;
  *(float4*)(row + c + 512) = y2;
  *(uint2*)(rb + c)       = make_uint2(pack2(y0.x, y0.y), pack2(y0.z, y0.w));
  *(uint2*)(rb + c + 256) = make_uint2(pack2(y1.x, y1.y), pack2(y1.z, y1.w));
  *(uint2*)(rb + c + 512) = make_uint2(pack2(y2.x, y2.y), pack2(y2.z, y2.w));
}

// ---------------- LayerNorm: wave-per-row, float4, no LDS/barrier ----------------
__global__ __launch_bounds__(256) void ln_kern(
    float* __restrict__ h, const float* __restrict__ g, const float* __restrict__ bb,
    u16* __restrict__ hb)
{
  const long i = (long)blockIdx.x * 4 + (threadIdx.x >> 6);
  const int lane = threadIdx.x & 63;
  const int c = lane * 4;
  float* row = h + i * D;
  u16* rb = hb + i * D;
  float4 x0 = *(const float4*)(row + c);
  float4 x1 = *(const float4*)(row + c + 256);
  float4 x2 = *(const float4*)(row + c + 512);
  float sm = x0.x+x0.y+x0.z+x0.w + x1.x+x1.y+x1.z+x1.w + x2.x+x2.y+x2.z+x2.w;
  float sq = x0.x*x0.x+x0.y*x0.y+x0.z*x0.z+x0.w*x0.w
           + x1.x*x1.x+x1.y*x1.y+x1.z*x1.z+x1.w*x1.w
           + x2.x*x2.x+x2.y*x2.y+x2.z*x2.z+x2.w*x2.w;
  #pragma unroll
  for (int o = 32; o; o >>= 1) { sm += __shfl_xor(sm, o); sq += __shfl_xor(sq, o); }
  const float mean = sm * (1.f / D);
  const float var  = sq * (1.f / D) - mean * mean;
  const float rs   = rsqrtf(var + 1e-12f);
  float4 g0 = *(const float4*)(g + c),  g1 = *(const float4*)(g + c + 256),
         g2 = *(const float4*)(g + c + 512);
  float4 b0 = *(const float4*)(bb + c), b1 = *(const float4*)(bb + c + 256),
         b2 = *(const float4*)(bb + c + 512);
  float4 y0 = make_float4((x0.x-mean)*rs*g0.x+b0.x, (x0.y-mean)*rs*g0.y+b0.y,
                          (x0.z-mean)*rs*g0.z+b0.z, (x0.w-mean)*rs*g0.w+b0.w);
  float4 y1 = make_float4((x1.x-mean)*rs*g1.x+b1.x, (x1.y-mean)*rs*g1.y+b1.y,
                          (x1.z-mean)*rs*g1.z+b1.z, (x1.w-mean)*rs*g1.w+b1.w);
  float4 y2 = make_float4((x2.x-mean)*rs*g2.x+b2.x, (x2.y-mean)*rs*g2.y+b2.y,
                          (x2.z-mean)*rs*g2.z+b2.z, (x2.w-mean)*rs*g2.w+b2.w);
  *(float4*)(row + c)       = y0;
  *(float4*)(row + c + 256) = y1;
  *(float4*)(row + c + 512) = y2;
  *(uint2*)(rb + c)       = make_uint2(pack2(y0.x, y0.y), pack2(y0.z, y0.w));
  *(uint2*)(rb + c + 256) = make_uint2(pack2(y1.x, y1.y), pack2(y1.z, y1.w));
  *(uint2*)(rb + c + 512) = make_uint2(pack2(y2.x, y2.y), pack2(y2.z, y2.w));
}

// ---------------- bf16 MFMA GEMM: BK=64, 2-stage, counted vmcnt + raw barriers ------
// (round-10 core, best known)
__global__ __launch_bounds__(256) void mgemm_kern(
    const u16* __restrict__ A, const u16* __restrict__ Wt,
    const float* __restrict__ bias, void* __restrict__ Cv,
    int N, int K, long wz, long bz, long cz, int mode, int ksplit)
{
  const int z = blockIdx.z;
  int k0 = 0, kend = K;
  if (ksplit > 1) {
    const int kch = K / ksplit;
    k0 = z * kch; kend = k0 + kch;
  } else {
    Wt += (long)z * wz; bias += (long)z * bz;
  }
  const int gx = gridDim.x;
  const int nwg = gx * gridDim.y;
  int bid = blockIdx.y * gx + blockIdx.x;
  bid = (bid & 7) * (nwg >> 3) + (bid >> 3);
  const long bm = (long)(bid / gx) * 128;
  const int bn = (bid % gx) * 128;

  const int tid = threadIdx.x;
  const int lane = tid & 63, w = tid >> 6;
  const int wm = w >> 1, wn = w & 1;
  const int ls = lane >> 4, lr = lane & 15;

  __shared__ u16 LB[32768];
  u16* const St0 = LB;
  u16* const St1 = LB + 16384;

  f32x4 acc[4][4];
  #pragma unroll
  for (int i = 0; i < 4; ++i)
    #pragma unroll
    for (int j = 0; j < 4; ++j)
      acc[i][j] = (f32x4){0.f, 0.f, 0.f, 0.f};

  auto STAGE = [&](u16* buf, int kk) {
    #pragma unroll
    for (int c = 0; c < 4; ++c) {
      const int n = (w * 4 + c) * 64 + lane;
      const int row = n >> 3;
      const int kc2 = (n & 7) ^ (row & 7);
      gload16(A  + (bm + row) * K + kk + kc2 * 8, buf + (w * 4 + c) * 512);
      gload16(Wt + (long)(bn + row) * K + kk + kc2 * 8, buf + 8192 + (w * 4 + c) * 512);
    }
  };

  STAGE(St0, k0);
  int cur = 0;
  for (int kk = k0; kk < kend; kk += 64) {
    if (kk + 64 < kend) {
      STAGE(cur ? St0 : St1, kk + 64);
      asm volatile("s_waitcnt vmcnt(8)" ::: "memory");
    } else {
      asm volatile("s_waitcnt vmcnt(0)" ::: "memory");
    }
    __builtin_amdgcn_s_barrier();
    __builtin_amdgcn_sched_barrier(0);
    const u16* AsL = cur ? St1 : St0;
    const u16* BsL = AsL + 8192;
    __builtin_amdgcn_s_setprio(1);
    #pragma unroll
    for (int ks = 0; ks < 2; ++ks) {
      bf16x8 af[4], bv[4];
      const int kc = ks * 4 + ls;
      const int sw = (kc ^ (lr & 7)) << 3;
      #pragma unroll
      for (int mf = 0; mf < 4; ++mf)
        af[mf] = *(const bf16x8*)&AsL[(wm * 64 + mf * 16 + lr) * 64 + sw];
      #pragma unroll
      for (int nf = 0; nf < 4; ++nf)
        bv[nf] = *(const bf16x8*)&BsL[(wn * 64 + nf * 16 + lr) * 64 + sw];
      #pragma unroll
      for (int mf = 0; mf < 4; ++mf)
        #pragma unroll
        for (int nf = 0; nf < 4; ++nf)
          acc[mf][nf] = __builtin_amdgcn_mfma_f32_16x16x32_bf16(
              af[mf], bv[nf], acc[mf][nf], 0, 0, 0);
    }
    __builtin_amdgcn_s_setprio(0);
    __builtin_amdgcn_s_barrier();
    cur ^= 1;
  }

  float* Cf = (float*)Cv + (long)z * cz;
  u16*   Cu = (u16*)Cv  + (long)z * cz;
  const int r0 = ls * 4;
  const bool addb = (ksplit == 1) || (z == 0);

  if (mode == 1 || (mode == 4 && bn < 1536)) {
    const int t = (mode == 4) ? (bn / 768) : 0;
    const int cl0 = (mode == 4) ? (bn - t * 768) : bn;
    const int Nt = (mode == 4) ? 768 : N;
    u16* Cd = (mode == 4) ? (Cu + (long)t * HD) : Cu;
    #pragma unroll
    for (int nf = 0; nf < 4; ++nf) {
      const int col = wn * 64 + nf * 16 + lr;
      const float bvv = bias[bn + col];
      #pragma unroll
      for (int mf = 0; mf < 4; ++mf) {
        #pragma unroll
        for (int r = 0; r < 4; ++r) {
          const int rowl = wm * 64 + mf * 16 + r0 + r;
          float vv = acc[mf][nf][r] + bvv;
          if (mode == 1) vv = fast_gelu(vv);
          LB[rowl * 128 + (col ^ ((rowl & 7) << 3))] = f2bf(vv);
        }
      }
    }
    __syncthreads();
    const int c0 = (tid & 15) * 8;
    #pragma unroll
    for (int i = 0; i < 8; ++i) {
      const int gr = (tid >> 4) + i * 16;
      uint4 v4 = *(const uint4*)&LB[gr * 128 + (c0 ^ ((gr & 7) << 3))];
      *(uint4*)(Cd + (bm + gr) * Nt + cl0 + c0) = v4;
    }
    return;
  }

  if (mode == 4) {
    #pragma unroll
    for (int nf = 0; nf < 4; ++nf) {
      const int cl = bn - 1536 + wn * 64 + nf * 16 + lr;
      const int hcol = cl >> 6, dcol = cl & 63;
      const float bvv = bias[1536 + cl];
      #pragma unroll
      for (int mf = 0; mf < 4; ++mf) {
        const long t0 = bm + wm * 64 + mf * 16 + r0;
        const int bb2 = (int)(t0 >> 12), s0 = (int)(t0 & (S - 1));
        const float v0 = acc[mf][nf][0] + bvv, v1 = acc[mf][nf][1] + bvv;
        const float v2 = acc[mf][nf][2] + bvv, v3 = acc[mf][nf][3] + bvv;
        *(uint2*)(Cu + 2 * HD + (((long)bb2 * H + hcol) * 64 + dcol) * S + s0) =
            make_uint2(pack2(v0, v1), pack2(v2, v3));
      }
    }
    return;
  }

  #pragma unroll
  for (int nf = 0; nf < 4; ++nf) {
    const int col = bn + wn * 64 + nf * 16 + lr;
    const float bvv = addb ? bias[col] : 0.f;
    #pragma unroll
    for (int mf = 0; mf < 4; ++mf) {
      #pragma unroll
      for (int r = 0; r < 4; ++r) {
        const long row = bm + wm * 64 + mf * 16 + r0 + r;
        float vv = acc[mf][nf][r] + bvv;
        if (mode == 2) {
          if (ksplit > 1) atomicAdd(&Cf[row * N + col], vv);
          else            Cf[row * N + col] += vv;
        } else {
          Cf[row * N + col] = vv;
        }
      }
    }
  }
}

// ---------------- MFMA block attention: swapped QK^T, defer-max, MFMA l-sum ---------
// 1D grid 1872 = B*H*78; XCD-chunked bijective remap (1872 = 8*234).
// Dense split into 8 chunks (nkv=8) so every block does exactly 8 KV tiles.
__global__ __launch_bounds__(256) void mattn_kern(
    const u16* __restrict__ q, const u16* __restrict__ k, const u16* __restrict__ vt,
    const float* __restrict__ mask, const int* __restrict__ rb,
    u16* __restrict__ ctx, float* __restrict__ part)
{
  int lin = blockIdx.x;
  lin = (lin & 7) * 234 + (lin >> 3);          // XCD-chunked (1872 = 8*234, bijective)
  const int x  = lin % 78;
  const int hh = (lin / 78) % H;
  const int b  = lin / 936;

  int qb, kv0, nkv, qb2 = 0, ch = 0, dense;
  if (x < 62) { dense = 0; qb = x + 1; kv0 = 0; nkv = NKV; }
  else {
    dense = 1;
    const int dx = x - 62;                      // 0..15
    qb2 = dx >> 3; ch = dx & 7;
    qb = qb2 ? NB - 1 : 0; kv0 = ch * (NB / NCH); nkv = NB / NCH;   // 8 tiles
  }
  const int tid = threadIdx.x, lane = tid & 63, w = tid >> 6;
  const int lr = lane & 15, hi = lane >> 4;

  __shared__ u16 KV[2][8192];    // per stage: K [0..4095] (swz), V^T [4096..8191] (swz)
  __shared__ u16 Ps[64][72];     // P tile (intra-wave) / ctx transpose buffer

  const long qrow0 = (long)b * S + qb * 64;
  bf16x8 qf[2];
  {
    const u16* qp = q + (qrow0 + w * 16 + lr) * D + hh * 64 + hi * 8;
    qf[0] = *(const bf16x8*)(qp);
    qf[1] = *(const bf16x8*)(qp + 32);
  }
  const long vtbase = (((long)b * H + hh) * 64) * S;

  bf16x8 ones8;
  #pragma unroll
  for (int i = 0; i < 8; ++i) ones8[i] = __builtin_bit_cast(bf16, (u16)0x3F80);

  auto kbof = [&](int j) -> int {
    if (dense) return kv0 + j;
    if (j < 3) return qb - 1 + j;
    if (j == 3) return 0;
    if (j == 4) return NB - 1;
    return rb[qb * 3 + (j - 5)];
  };

  auto STAGE = [&](u16* st, int kb) {   // 4 gload16 per wave
    const long krow0 = (long)b * S + kb * 64;
    #pragma unroll
    for (int c = 0; c < 2; ++c) {
      const int n = (w * 2 + c) * 64 + lane;
      const int row = n >> 3;
      const int g2 = (n & 7) ^ (row & 7);
      gload16(k + (krow0 + row) * D + hh * 64 + g2 * 8, st + (w * 2 + c) * 512);
      gload16(vt + vtbase + (long)row * S + kb * 64 + g2 * 8, st + 4096 + (w * 2 + c) * 512);
    }
  };

  f32x4 acc[4];
  #pragma unroll
  for (int nf = 0; nf < 4; ++nf) acc[nf] = (f32x4){0.f, 0.f, 0.f, 0.f};
  f32x4 lacc = (f32x4){0.f, 0.f, 0.f, 0.f};      // row-sums of P (rows = hi*4+r)
  float m_run = -1e30f;                           // my q-row (w*16+lr), log2 domain

  const float C2 = SCALE * L2E;

  float4 mk4[4];
  auto LOADMASK = [&](int kb) {
    const long r = (long)b * S + kb * 64;
    #pragma unroll
    for (int kf = 0; kf < 4; ++kf)
      mk4[kf] = *(const float4*)(mask + r + kf * 16 + hi * 4);
  };

  STAGE(KV[0], kbof(0));
  LOADMASK(kbof(0));

  for (int jj = 0; jj < nkv; ++jj) {
    if (jj + 1 < nkv) {
      STAGE(KV[(jj + 1) & 1], kbof(jj + 1));
      asm volatile("s_waitcnt vmcnt(4)" ::: "memory");
    } else {
      asm volatile("s_waitcnt vmcnt(0)" ::: "memory");
    }
    __builtin_amdgcn_s_barrier();
    __builtin_amdgcn_sched_barrier(0);

    const u16* Ks = KV[jj & 1];
    const u16* Vs = Ks + 4096;

    // ---- QK^T swapped: C[key][q]; sc[kf][r] = score(key=kf*16+hi*4+r, q=w*16+lr)
    f32x4 sc[4];
    #pragma unroll
    for (int kf = 0; kf < 4; ++kf) sc[kf] = (f32x4){0.f, 0.f, 0.f, 0.f};
    __builtin_amdgcn_s_setprio(1);
    #pragma unroll
    for (int kc = 0; kc < 2; ++kc) {
      #pragma unroll
      for (int kf = 0; kf < 4; ++kf) {
        const int g2 = ((kc * 4 + hi) ^ (lr & 7)) << 3;
        bf16x8 kfr = *(const bf16x8*)&Ks[(kf * 16 + lr) * 64 + g2];
        sc[kf] = __builtin_amdgcn_mfma_f32_16x16x32_bf16(kfr, qf[kc], sc[kf], 0, 0, 0);
      }
    }
    __builtin_amdgcn_s_setprio(0);

    // ---- in-lane softmax (exp2 domain); mask preloaded (mk4)
    float sv[4][4];
    float mx = -3.0e38f;
    #pragma unroll
    for (int kf = 0; kf < 4; ++kf) {
      const float mka[4] = {mk4[kf].x, mk4[kf].y, mk4[kf].z, mk4[kf].w};
      #pragma unroll
      for (int r = 0; r < 4; ++r) {
        sv[kf][r] = sc[kf][r] * C2 + (mka[r] - 1.f) * (1e9f * L2E);
        mx = fmaxf(mx, sv[kf][r]);
      }
    }
    mx = fmaxf(mx, __shfl_xor(mx, 16));
    mx = fmaxf(mx, __shfl_xor(mx, 32));
    const bool need = mx > m_run + 8.f;
    if (__any((int)need)) {                 // T13 defer-max
      const float mn = fmaxf(m_run, mx);
      const float al = exp2f(m_run - mn);
      m_run = mn;
      #pragma unroll
      for (int r = 0; r < 4; ++r) {
        const float alr = __shfl(al, (lane & 48) | (hi * 4 + r));
        lacc[r] *= alr;
        acc[0][r] *= alr; acc[1][r] *= alr; acc[2][r] *= alr; acc[3][r] *= alr;
      }
    }
    {
      const int prow = w * 16 + lr;          // my q-row; 4 packed uint2 stores
      #pragma unroll
      for (int kf = 0; kf < 4; ++kf) {
        u32 lo = pack2(exp2f(sv[kf][0] - m_run), exp2f(sv[kf][1] - m_run));
        u32 hi2 = pack2(exp2f(sv[kf][2] - m_run), exp2f(sv[kf][3] - m_run));
        *(uint2*)&Ps[prow][kf * 16 + hi * 4] = make_uint2(lo, hi2);
      }
    }

    // ---- PV + l-sum
    __builtin_amdgcn_s_setprio(1);
    #pragma unroll
    for (int kc = 0; kc < 2; ++kc) {
      bf16x8 pf = *(const bf16x8*)&Ps[w * 16 + lr][kc * 32 + hi * 8];
      #pragma unroll
      for (int nf = 0; nf < 4; ++nf) {
        const int g2 = ((kc * 4 + hi) ^ (lr & 7)) << 3;
        bf16x8 vfr = *(const bf16x8*)&Vs[(nf * 16 + lr) * 64 + g2];
        acc[nf] = __builtin_amdgcn_mfma_f32_16x16x32_bf16(pf, vfr, acc[nf], 0, 0, 0);
      }
      lacc = __builtin_amdgcn_mfma_f32_16x16x32_bf16(pf, ones8, lacc, 0, 0, 0);
    }
    __builtin_amdgcn_s_setprio(0);

    if (jj + 1 < nkv) LOADMASK(kbof(jj + 1));   // prefetch next tile's mask

    __builtin_amdgcn_s_barrier();    // KV[jj&1] reads done; free for next iter's STAGE
  }

  if (!dense) {
    // coalesced ctx store via Ps transpose
    #pragma unroll
    for (int r = 0; r < 4; ++r) {
      const float inv = 1.f / lacc[r];
      const int prow = w * 16 + hi * 4 + r;
      Ps[prow][ 0 + lr] = f2bf(acc[0][r] * inv);
      Ps[prow][16 + lr] = f2bf(acc[1][r] * inv);
      Ps[prow][32 + lr] = f2bf(acc[2][r] * inv);
      Ps[prow][48 + lr] = f2bf(acc[3][r] * inv);
    }
    __syncthreads();
    const int r2 = tid >> 2, c2 = (tid & 3) * 16;
    uint4 v0 = *(const uint4*)&Ps[r2][c2];
    uint4 v1 = *(const uint4*)&Ps[r2][c2 + 8];
    u16* op = ctx + (qrow0 + r2) * D + hh * 64 + c2;
    *(uint4*)(op)     = v0;
    *(uint4*)(op + 8) = v1;
  } else {
    const long pb = ((((long)b * H + hh) * 2 + qb2) * NCH + ch) * (64 * 68);
    #pragma unroll
    for (int r = 0; r < 4; ++r) {
      const float m_r = __shfl(m_run, (lane & 48) | (hi * 4 + r));
      float* pp = part + pb + (w * 16 + hi * 4 + r) * 68;
      pp[ 0 + lr] = acc[0][r];
      pp[16 + lr] = acc[1][r];
      pp[32 + lr] = acc[2][r];
      pp[48 + lr] = acc[3][r];
      if (lr == 0) { pp[64] = m_r; pp[65] = lacc[r]; }  // m in log2 domain
    }
  }
}

// ---------------- combine dense split-K partials (exp2 domain) ----------------
__global__ __launch_bounds__(256) void attn_combine_kern(
    const float* __restrict__ part, u16* __restrict__ ctx)
{
  const int g = blockIdx.x;
  const int qb2 = g & 1;
  const int hh = (g >> 1) % H;
  const int b  = g / (2 * H);
  const int r  = threadIdx.x >> 2;
  const int d0 = (threadIdx.x & 3) * 16;
  const long pb = (long)g * NCH * 64 * 68;
  float mg = -1e30f;
  for (int ch = 0; ch < NCH; ++ch)
    mg = fmaxf(mg, part[pb + ch * 64 * 68 + r * 68 + 64]);
  float lg = 0.f;
  float a[16] = {};
  for (int ch = 0; ch < NCH; ++ch) {
    const float* pp = part + pb + ch * 64 * 68 + r * 68;
    const float w = exp2f(pp[64] - mg);
    lg += pp[65] * w;
    #pragma unroll
    for (int i = 0; i < 4; ++i) {
      float4 t4 = *(const float4*)(pp + d0 + i * 4);
      a[i*4+0] += t4.x * w; a[i*4+1] += t4.y * w; a[i*4+2] += t4.z * w; a[i*4+3] += t4.w * w;
    }
  }
  const int qb = qb2 ? NB - 1 : 0;
  const float inv = 1.f / lg;
  u16* op = ctx + ((long)b * S + qb * 64 + r) * D + hh * 64 + d0;
  #pragma unroll
  for (int i = 0; i < 4; ++i)
    *(uint2*)(op + i * 4) = make_uint2(pack2(a[i*4+0]*inv, a[i*4+1]*inv),
                                       pack2(a[i*4+2]*inv, a[i*4+3]*inv));
}

// ---------------- span mean-pool + head ----------------
__global__ __launch_bounds__(256) void span_head_kern(
    const float* __restrict__ h, const int* __restrict__ spans,
    const float* __restrict__ hw, const float* __restrict__ hb, float* __restrict__ out)
{
  __shared__ float s0[4], s1[4];
  const int bn = blockIdx.x;
  const int tid = threadIdx.x;
  const int st = spans[bn * 2], en = spans[bn * 2 + 1];
  const int b = bn >> 3;
  float a0 = 0.f, a1 = 0.f, a2 = 0.f;
  for (int s = st; s < en; ++s) {
    const float* row = h + ((long)b * S + s) * D;
    a0 += row[tid]; a1 += row[tid + 256]; a2 += row[tid + 512];
  }
  const float inv = 1.f / (float)(en - st);
  a0 *= inv; a1 *= inv; a2 *= inv;
  float p0 = a0 * hw[tid * 2]     + a1 * hw[(tid + 256) * 2]     + a2 * hw[(tid + 512) * 2];
  float p1 = a0 * hw[tid * 2 + 1] + a1 * hw[(tid + 256) * 2 + 1] + a2 * hw[(tid + 512) * 2 + 1];
  #pragma unroll
  for (int o = 32; o; o >>= 1) { p0 += __shfl_xor(p0, o); p1 += __shfl_xor(p1, o); }
  if ((tid & 63) == 0) { s0[tid >> 6] = p0; s1[tid >> 6] = p1; }
  __syncthreads();
  if (tid == 0) {
    out[bn * 2]     = s0[0] + s0[1] + s0[2] + s0[3] + hb[0];
    out[bn * 2 + 1] = s1[0] + s1[1] + s1[2] + s1[3] + hb[1];
  }
}

// ---------------- launcher ----------------
extern "C" void kernel_launch(void* const* d_in, const int* in_sizes, int n_in,
                              void* d_out, int out_size, void* d_ws, size_t ws_size,
                              hipStream_t stream) {
  const int*   input_ids  = (const int*)  d_in[0];
  const float* attn_mask  = (const float*)d_in[1];
  const int*   tok_type   = (const int*)  d_in[2];
  const int*   spans      = (const int*)  d_in[3];
  const int*   rand_blk   = (const int*)  d_in[4];
  const float* word_emb   = (const float*)d_in[5];
  const float* pos_emb    = (const float*)d_in[6];
  const float* type_emb   = (const float*)d_in[7];
  const float* emb_g      = (const float*)d_in[8];
  const float* emb_b      = (const float*)d_in[9];
  const float* qkv_w      = (const float*)d_in[10];
  const float* qkv_b      = (const float*)d_in[11];
  const float* aow        = (const float*)d_in[12];
  const float* aob        = (const float*)d_in[13];
  const float* ln1g       = (const float*)d_in[14];
  const float* ln1b       = (const float*)d_in[15];
  const float* ff1w       = (const float*)d_in[16];
  const float* ff1b       = (const float*)d_in[17];
  const float* ff2w       = (const float*)d_in[18];
  const float* ff2b       = (const float*)d_in[19];
  const float* ln2g       = (const float*)d_in[20];
  const float* ln2b       = (const float*)d_in[21];
  const float* headw      = (const float*)d_in[22];
  const float* headb      = (const float*)d_in[23];

  float* ws    = (float*)d_ws;
  float* h     = ws;                          // [M,D] fp32
  u16*   qkvb  = (u16*)(ws + HD);             // q,k bf16 [M,D]; vt [B,H,64,S]
  u16*   ffb   = (u16*)(ws + HD);             // [M,F] bf16 overlays qkv region
  u16*   ctx16 = (u16*)(ws + 3 * HD);         // [M,D] bf16
  u16*   hb    = (u16*)(ws + 3 * HD + HD/2);  // [M,D] bf16
  float* part  = ws + 4 * HD;                 // dense partials: 2*12*2*8*64*68 ~1.67M floats
  u16*   wb    = (u16*)(ws + 4 * HD + HD/2);  // bf16 weights: [qkv6][ao2][ff1x2][ff2x2]

  // ---- weight prep (bf16 transposed), z-batched across both layers: 4 launches ----
  wtrans_kern<<<dim3(24, 24, 6), dim3(256), 0, stream>>>(qkv_w, wb, D, D, DD, DD);
  wtrans_kern<<<dim3(24, 24, 2), dim3(256), 0, stream>>>(aow, wb + OFF_AO, D, D, DD, DD);
  wtrans_kern<<<dim3(96, 24, 2), dim3(256), 0, stream>>>(ff1w, wb + OFF_FF1, D, F, DF, DF);
  wtrans_kern<<<dim3(24, 96, 2), dim3(256), 0, stream>>>(ff2w, wb + OFF_FF2, F, D, DF, DF);

  embed_ln_kern<<<dim3(M / 4), dim3(256), 0, stream>>>(
      input_ids, tok_type, word_emb, pos_emb, type_emb, emb_g, emb_b, h, hb);

  for (int l = 0; l < 2; ++l) {
    // merged QKV projection (N=2304): q,k coalesced bf16; v transposed [b,h,d,S]
    mgemm_kern<<<dim3(18, 64, 1), dim3(256), 0, stream>>>(
        hb, wb + (long)l * 3 * DD, qkv_b + (long)l * 3 * D, qkvb, 2304, D, 0, 0, 0, 4, 1);
    // block attention: 1D XCD-chunked grid (sparse 62 + dense 16 per (b,h), 8 tiles each)
    mattn_kern<<<dim3(1872), dim3(256), 0, stream>>>(
        qkvb, qkvb + HD, qkvb + 2 * HD, attn_mask, rand_blk, ctx16, part);
    attn_combine_kern<<<dim3(B * H * 2), dim3(256), 0, stream>>>(part, ctx16);
    // output projection + residual into h (ksplit=1: all-resident, no atomics)
    mgemm_kern<<<dim3(6, 64, 1), dim3(256), 0, stream>>>(
        ctx16, wb + OFF_AO + (long)l * DD, aob + (long)l * D, h, D, D, 0, 0, 0, 2, 1);
    ln_kern<<<dim3(M / 4), dim3(256), 0, stream>>>(h, ln1g + (long)l * D, ln1b + (long)l * D, hb);
    // FFN
    mgemm_kern<<<dim3(24, 64, 1), dim3(256), 0, stream>>>(
        hb, wb + OFF_FF1 + (long)l * DF, ff1b + (long)l * F, ffb, F, D, 0, 0, 0, 1, 1);
    mgemm_kern<<<dim3(6, 64, 1), dim3(256), 0, stream>>>(
        ffb, wb + OFF_FF2 + (long)l * DF, ff2b + (long)l * D, h, D, F, 0, 0, 0, 2, 1);
    ln_kern<<<dim3(M / 4), dim3(256), 0, stream>>>(h, ln2g + (long)l * D, ln2b + (long)l * D, hb);
  }

  span_head_kern<<<dim3(B * NS), dim3(256), 0, stream>>>(h, spans, headw, headb, (float*)d_out);
}

// Round 23
// 545.936 us; speedup vs baseline: 1.1948x; 1.1281x over previous
//
#include <hip/hip_runtime.h>

// ---------------- constants ----------------
constexpr int B = 2, S = 4096, D = 768, H = 12, DH = 64, BLK = 64, NB = 64, NKV = 8;
constexpr int F = 3072, NS = 8, M = B * S;            // M = 8192 tokens
constexpr int NCH = 8;                                 // dense split chunks (nkv=8 each)
constexpr float SCALE = 0.125f;                        // 1/sqrt(64)
constexpr float L2E = 1.44269504088896f;               // log2(e)
constexpr long HD = (long)M * D;                       // 6291456 elems per [M,D] buffer

using u16 = unsigned short;
using u32 = unsigned int;
using bf16 = __bf16;
using bf16x8 = __attribute__((ext_vector_type(8))) bf16;
using f32x4 = __attribute__((ext_vector_type(4))) float;

// bf16 weight region layout (u16 counts): [qkv x6 DD][ao x2 DD][ff1 x2 DF][ff2 x2 FD]
constexpr long DD = (long)D * D;
constexpr long DF = (long)D * F;
constexpr long OFF_AO  = 6 * DD;
constexpr long OFF_FF1 = 8 * DD;
constexpr long OFF_FF2 = 8 * DD + 2 * DF;

__device__ __forceinline__ u16 f2bf(float x) {
  u32 u = __builtin_bit_cast(u32, x);
  u = (u + 0x7fffu + ((u >> 16) & 1u)) >> 16;
  return (u16)u;
}
__device__ __forceinline__ u32 pack2(float a, float b) {
  return (u32)f2bf(a) | ((u32)f2bf(b) << 16);
}
__device__ __forceinline__ float bf2f(u16 v) {
  return __builtin_bit_cast(float, (u32)v << 16);
}
// fast tanh-gelu: 0.5x(1+tanh(u)) == x - x/(exp(2u)+1); inf-safe both tails
__device__ __forceinline__ float fast_gelu(float x) {
  float u = 0.7978845608028654f * (x + 0.044715f * x * x * x);
  float t = __expf(u + u);
  return x - x * __builtin_amdgcn_rcpf(t + 1.f);
}

// async 16B global -> LDS (dest = wave-uniform base + lane*16)
__device__ __forceinline__ void gload16(const void* g, void* l) {
  __builtin_amdgcn_global_load_lds(
      (const __attribute__((address_space(1))) u32*)g,
      (__attribute__((address_space(3))) u32*)l, 16, 0, 0);
}

// ---------------- weight transpose + cast: out[n][k] = bf16(in[k][n]) ----------------
__global__ __launch_bounds__(256) void wtrans_kern(
    const float* __restrict__ in, u16* __restrict__ out, int K, int N, long inz, long outz)
{
  in += (long)blockIdx.z * inz; out += (long)blockIdx.z * outz;
  __shared__ float T[32][33];
  const int n0 = blockIdx.x * 32, k0 = blockIdx.y * 32;
  const int c = threadIdx.x & 31, r8 = threadIdx.x >> 5;
  #pragma unroll
  for (int i = 0; i < 4; ++i)
    T[r8 + i * 8][c] = in[(long)(k0 + r8 + i * 8) * N + n0 + c];
  __syncthreads();
  #pragma unroll
  for (int i = 0; i < 4; ++i)
    out[(long)(n0 + r8 + i * 8) * K + k0 + c] = f2bf(T[c][r8 + i * 8]);
}

// ---------------- embedding + LN: wave-per-row, bf16 h out ----------------
__global__ __launch_bounds__(256) void embed_ln_kern(
    const int* __restrict__ ids, const int* __restrict__ tt,
    const float* __restrict__ we, const float* __restrict__ pe, const float* __restrict__ te,
    const float* __restrict__ g, const float* __restrict__ bb,
    u16* __restrict__ h)
{
  const long i = (long)blockIdx.x * 4 + (threadIdx.x >> 6);
  const int lane = threadIdx.x & 63;
  const int c = lane * 4;
  const int s = (int)(i & (S - 1));
  const long wo = (long)ids[i] * D;
  const long to = (long)tt[i] * D;
  const long po = (long)s * D;
  float4 x0, x1, x2;
  {
    float4 a0 = *(const float4*)(we + wo + c),       p0 = *(const float4*)(pe + po + c),
           t0 = *(const float4*)(te + to + c);
    float4 a1 = *(const float4*)(we + wo + c + 256), p1 = *(const float4*)(pe + po + c + 256),
           t1 = *(const float4*)(te + to + c + 256);
    float4 a2 = *(const float4*)(we + wo + c + 512), p2 = *(const float4*)(pe + po + c + 512),
           t2 = *(const float4*)(te + to + c + 512);
    x0 = make_float4(a0.x+p0.x+t0.x, a0.y+p0.y+t0.y, a0.z+p0.z+t0.z, a0.w+p0.w+t0.w);
    x1 = make_float4(a1.x+p1.x+t1.x, a1.y+p1.y+t1.y, a1.z+p1.z+t1.z, a1.w+p1.w+t1.w);
    x2 = make_float4(a2.x+p2.x+t2.x, a2.y+p2.y+t2.y, a2.z+p2.z+t2.z, a2.w+p2.w+t2.w);
  }
  float sm = x0.x+x0.y+x0.z+x0.w + x1.x+x1.y+x1.z+x1.w + x2.x+x2.y+x2.z+x2.w;
  float sq = x0.x*x0.x+x0.y*x0.y+x0.z*x0.z+x0.w*x0.w
           + x1.x*x1.x+x1.y*x1.y+x1.z*x1.z+x1.w*x1.w
           + x2.x*x2.x+x2.y*x2.y+x2.z*x2.z+x2.w*x2.w;
  #pragma unroll
  for (int o = 32; o; o >>= 1) { sm += __shfl_xor(sm, o); sq += __shfl_xor(sq, o); }
  const float mean = sm * (1.f / D);
  const float var  = sq * (1.f / D) - mean * mean;
  const float rs   = rsqrtf(var + 1e-12f);
  float4 g0 = *(const float4*)(g + c),  g1 = *(const float4*)(g + c + 256),
         g2 = *(const float4*)(g + c + 512);
  float4 b0 = *(const float4*)(bb + c), b1 = *(const float4*)(bb + c + 256),
         b2 = *(const float4*)(bb + c + 512);
  u16* rb = h + i * D;
  *(uint2*)(rb + c)       = make_uint2(pack2((x0.x-mean)*rs*g0.x+b0.x, (x0.y-mean)*rs*g0.y+b0.y),
                                       pack2((x0.z-mean)*rs*g0.z+b0.z, (x0.w-mean)*rs*g0.w+b0.w));
  *(uint2*)(rb + c + 256) = make_uint2(pack2((x1.x-mean)*rs*g1.x+b1.x, (x1.y-mean)*rs*g1.y+b1.y),
                                       pack2((x1.z-mean)*rs*g1.z+b1.z, (x1.w-mean)*rs*g1.w+b1.w));
  *(uint2*)(rb + c + 512) = make_uint2(pack2((x2.x-mean)*rs*g2.x+b2.x, (x2.y-mean)*rs*g2.y+b2.y),
                                       pack2((x2.z-mean)*rs*g2.z+b2.z, (x2.w-mean)*rs*g2.w+b2.w));
}

// ---------------- LayerNorm: wave-per-row over bf16 h, in place ----------------
__global__ __launch_bounds__(256) void ln_kern(
    u16* __restrict__ h, const float* __restrict__ g, const float* __restrict__ bb)
{
  const long i = (long)blockIdx.x * 4 + (threadIdx.x >> 6);
  const int lane = threadIdx.x & 63;
  const int c = lane * 4;
  u16* row = h + i * D;
  uint2 u0 = *(const uint2*)(row + c);
  uint2 u1 = *(const uint2*)(row + c + 256);
  uint2 u2 = *(const uint2*)(row + c + 512);
  float x[12];
  x[0] = bf2f(u0.x); x[1] = bf2f(u0.x >> 16); x[2] = bf2f(u0.y); x[3] = bf2f(u0.y >> 16);
  x[4] = bf2f(u1.x); x[5] = bf2f(u1.x >> 16); x[6] = bf2f(u1.y); x[7] = bf2f(u1.y >> 16);
  x[8] = bf2f(u2.x); x[9] = bf2f(u2.x >> 16); x[10] = bf2f(u2.y); x[11] = bf2f(u2.y >> 16);
  float sm = 0.f, sq = 0.f;
  #pragma unroll
  for (int j = 0; j < 12; ++j) { sm += x[j]; sq += x[j] * x[j]; }
  #pragma unroll
  for (int o = 32; o; o >>= 1) { sm += __shfl_xor(sm, o); sq += __shfl_xor(sq, o); }
  const float mean = sm * (1.f / D);
  const float var  = sq * (1.f / D) - mean * mean;
  const float rs   = rsqrtf(var + 1e-12f);
  float4 g0 = *(const float4*)(g + c),  g1 = *(const float4*)(g + c + 256),
         g2 = *(const float4*)(g + c + 512);
  float4 b0 = *(const float4*)(bb + c), b1 = *(const float4*)(bb + c + 256),
         b2 = *(const float4*)(bb + c + 512);
  *(uint2*)(row + c)       = make_uint2(pack2((x[0]-mean)*rs*g0.x+b0.x, (x[1]-mean)*rs*g0.y+b0.y),
                                        pack2((x[2]-mean)*rs*g0.z+b0.z, (x[3]-mean)*rs*g0.w+b0.w));
  *(uint2*)(row + c + 256) = make_uint2(pack2((x[4]-mean)*rs*g1.x+b1.x, (x[5]-mean)*rs*g1.y+b1.y),
                                        pack2((x[6]-mean)*rs*g1.z+b1.z, (x[7]-mean)*rs*g1.w+b1.w));
  *(uint2*)(row + c + 512) = make_uint2(pack2((x[8]-mean)*rs*g2.x+b2.x, (x[9]-mean)*rs*g2.y+b2.y),
                                        pack2((x[10]-mean)*rs*g2.z+b2.z, (x[11]-mean)*rs*g2.w+b2.w));
}

// ---------------- bf16 MFMA GEMM: BK=64, 2-stage, counted vmcnt + raw barriers ------
// mode 1: fast-gelu -> bf16 coalesced store via LDS transpose;
// mode 2: bf16 residual add, fp32 LDS transpose + coalesced uint4 RMW;
// mode 4: merged QKV (N=2304).
__global__ __launch_bounds__(256) void mgemm_kern(
    const u16* __restrict__ A, const u16* __restrict__ Wt,
    const float* __restrict__ bias, void* __restrict__ Cv,
    int N, int K, long wz, long bz, long cz, int mode, int ksplit)
{
  const int z = blockIdx.z;
  int k0 = 0, kend = K;
  if (ksplit > 1) {
    const int kch = K / ksplit;
    k0 = z * kch; kend = k0 + kch;
  } else {
    Wt += (long)z * wz; bias += (long)z * bz;
  }
  const int gx = gridDim.x;
  const int nwg = gx * gridDim.y;
  int bid = blockIdx.y * gx + blockIdx.x;
  bid = (bid & 7) * (nwg >> 3) + (bid >> 3);
  const long bm = (long)(bid / gx) * 128;
  const int bn = (bid % gx) * 128;

  const int tid = threadIdx.x;
  const int lane = tid & 63, w = tid >> 6;
  const int wm = w >> 1, wn = w & 1;
  const int ls = lane >> 4, lr = lane & 15;

  __shared__ u16 LB[32768];            // 64KB: two 32KB stages; epilogue reuses (u16 or f32)
  u16* const St0 = LB;
  u16* const St1 = LB + 16384;
  float* const LBf = (float*)LB;       // [128][128] f32 view for mode-2 epilogue

  f32x4 acc[4][4];
  #pragma unroll
  for (int i = 0; i < 4; ++i)
    #pragma unroll
    for (int j = 0; j < 4; ++j)
      acc[i][j] = (f32x4){0.f, 0.f, 0.f, 0.f};

  auto STAGE = [&](u16* buf, int kk) {
    #pragma unroll
    for (int c = 0; c < 4; ++c) {
      const int n = (w * 4 + c) * 64 + lane;
      const int row = n >> 3;
      const int kc2 = (n & 7) ^ (row & 7);
      gload16(A  + (bm + row) * K + kk + kc2 * 8, buf + (w * 4 + c) * 512);
      gload16(Wt + (long)(bn + row) * K + kk + kc2 * 8, buf + 8192 + (w * 4 + c) * 512);
    }
  };

  STAGE(St0, k0);
  int cur = 0;
  for (int kk = k0; kk < kend; kk += 64) {
    if (kk + 64 < kend) {
      STAGE(cur ? St0 : St1, kk + 64);
      asm volatile("s_waitcnt vmcnt(8)" ::: "memory");
    } else {
      asm volatile("s_waitcnt vmcnt(0)" ::: "memory");
    }
    __builtin_amdgcn_s_barrier();
    __builtin_amdgcn_sched_barrier(0);
    const u16* AsL = cur ? St1 : St0;
    const u16* BsL = AsL + 8192;
    __builtin_amdgcn_s_setprio(1);
    #pragma unroll
    for (int ks = 0; ks < 2; ++ks) {
      bf16x8 af[4], bv[4];
      const int kc = ks * 4 + ls;
      const int sw = (kc ^ (lr & 7)) << 3;
      #pragma unroll
      for (int mf = 0; mf < 4; ++mf)
        af[mf] = *(const bf16x8*)&AsL[(wm * 64 + mf * 16 + lr) * 64 + sw];
      #pragma unroll
      for (int nf = 0; nf < 4; ++nf)
        bv[nf] = *(const bf16x8*)&BsL[(wn * 64 + nf * 16 + lr) * 64 + sw];
      #pragma unroll
      for (int mf = 0; mf < 4; ++mf)
        #pragma unroll
        for (int nf = 0; nf < 4; ++nf)
          acc[mf][nf] = __builtin_amdgcn_mfma_f32_16x16x32_bf16(
              af[mf], bv[nf], acc[mf][nf], 0, 0, 0);
    }
    __builtin_amdgcn_s_setprio(0);
    __builtin_amdgcn_s_barrier();
    cur ^= 1;
  }

  u16* Cu = (u16*)Cv + (long)z * cz;
  const int r0 = ls * 4;

  if (mode == 2) {
    // residual add into bf16 h: fp32 LDS transpose, then coalesced uint4 RMW
    #pragma unroll
    for (int nf = 0; nf < 4; ++nf) {
      const int col = wn * 64 + nf * 16 + lr;
      const float bvv = bias[bn + col];
      #pragma unroll
      for (int mf = 0; mf < 4; ++mf) {
        #pragma unroll
        for (int r = 0; r < 4; ++r) {
          const int rowl = wm * 64 + mf * 16 + r0 + r;
          LBf[rowl * 128 + (col ^ ((rowl & 7) << 3))] = acc[mf][nf][r] + bvv;
        }
      }
    }
    __syncthreads();
    const int c0 = (tid & 15) * 8;
    #pragma unroll
    for (int i = 0; i < 8; ++i) {
      const int gr = (tid >> 4) + i * 16;
      const int cs = c0 ^ ((gr & 7) << 3);
      float4 a4 = *(const float4*)&LBf[gr * 128 + cs];
      float4 b4 = *(const float4*)&LBf[gr * 128 + cs + 4];
      u16* dst = Cu + (bm + gr) * N + bn + c0;
      uint4 res = *(const uint4*)dst;
      uint4 out;
      out.x = pack2(a4.x + bf2f(res.x), a4.y + bf2f(res.x >> 16));
      out.y = pack2(a4.z + bf2f(res.y), a4.w + bf2f(res.y >> 16));
      out.z = pack2(b4.x + bf2f(res.z), b4.y + bf2f(res.z >> 16));
      out.w = pack2(b4.z + bf2f(res.w), b4.w + bf2f(res.w >> 16));
      *(uint4*)dst = out;
    }
    return;
  }

  if (mode == 1 || (mode == 4 && bn < 1536)) {
    const int t = (mode == 4) ? (bn / 768) : 0;
    const int cl0 = (mode == 4) ? (bn - t * 768) : bn;
    const int Nt = (mode == 4) ? 768 : N;
    u16* Cd = (mode == 4) ? (Cu + (long)t * HD) : Cu;
    #pragma unroll
    for (int nf = 0; nf < 4; ++nf) {
      const int col = wn * 64 + nf * 16 + lr;
      const float bvv = bias[bn + col];
      #pragma unroll
      for (int mf = 0; mf < 4; ++mf) {
        #pragma unroll
        for (int r = 0; r < 4; ++r) {
          const int rowl = wm * 64 + mf * 16 + r0 + r;
          float vv = acc[mf][nf][r] + bvv;
          if (mode == 1) vv = fast_gelu(vv);
          LB[rowl * 128 + (col ^ ((rowl & 7) << 3))] = f2bf(vv);
        }
      }
    }
    __syncthreads();
    const int c0 = (tid & 15) * 8;
    #pragma unroll
    for (int i = 0; i < 8; ++i) {
      const int gr = (tid >> 4) + i * 16;
      uint4 v4 = *(const uint4*)&LB[gr * 128 + (c0 ^ ((gr & 7) << 3))];
      *(uint4*)(Cd + (bm + gr) * Nt + cl0 + c0) = v4;
    }
    return;
  }

  // mode 4, V columns: store transposed [b][h][d][S] bf16
  #pragma unroll
  for (int nf = 0; nf < 4; ++nf) {
    const int cl = bn - 1536 + wn * 64 + nf * 16 + lr;
    const int hcol = cl >> 6, dcol = cl & 63;
    const float bvv = bias[1536 + cl];
    #pragma unroll
    for (int mf = 0; mf < 4; ++mf) {
      const long t0 = bm + wm * 64 + mf * 16 + r0;
      const int bb2 = (int)(t0 >> 12), s0 = (int)(t0 & (S - 1));
      const float v0 = acc[mf][nf][0] + bvv, v1 = acc[mf][nf][1] + bvv;
      const float v2 = acc[mf][nf][2] + bvv, v3 = acc[mf][nf][3] + bvv;
      *(uint2*)(Cu + 2 * HD + (((long)bb2 * H + hcol) * 64 + dcol) * S + s0) =
          make_uint2(pack2(v0, v1), pack2(v2, v3));
    }
  }
}

// ---------------- MFMA block attention: swapped QK^T, defer-max, MFMA l-sum ---------
// 1D grid 1872 = B*H*78; XCD-chunked bijective remap (1872 = 8*234).
__global__ __launch_bounds__(256) void mattn_kern(
    const u16* __restrict__ q, const u16* __restrict__ k, const u16* __restrict__ vt,
    const float* __restrict__ mask, const int* __restrict__ rb,
    u16* __restrict__ ctx, float* __restrict__ part)
{
  int lin = blockIdx.x;
  lin = (lin & 7) * 234 + (lin >> 3);          // XCD-chunked (1872 = 8*234, bijective)
  const int x  = lin % 78;
  const int hh = (lin / 78) % H;
  const int b  = lin / 936;

  int qb, kv0, nkv, qb2 = 0, ch = 0, dense;
  if (x < 62) { dense = 0; qb = x + 1; kv0 = 0; nkv = NKV; }
  else {
    dense = 1;
    const int dx = x - 62;                      // 0..15
    qb2 = dx >> 3; ch = dx & 7;
    qb = qb2 ? NB - 1 : 0; kv0 = ch * (NB / NCH); nkv = NB / NCH;   // 8 tiles
  }
  const int tid = threadIdx.x, lane = tid & 63, w = tid >> 6;
  const int lr = lane & 15, hi = lane >> 4;

  __shared__ u16 KV[2][8192];    // per stage: K [0..4095] (swz), V^T [4096..8191] (swz)
  __shared__ u16 Ps[64][72];     // P tile (intra-wave) / ctx transpose buffer

  const long qrow0 = (long)b * S + qb * 64;
  bf16x8 qf[2];
  {
    const u16* qp = q + (qrow0 + w * 16 + lr) * D + hh * 64 + hi * 8;
    qf[0] = *(const bf16x8*)(qp);
    qf[1] = *(const bf16x8*)(qp + 32);
  }
  const long vtbase = (((long)b * H + hh) * 64) * S;

  bf16x8 ones8;
  #pragma unroll
  for (int i = 0; i < 8; ++i) ones8[i] = __builtin_bit_cast(bf16, (u16)0x3F80);

  auto kbof = [&](int j) -> int {
    if (dense) return kv0 + j;
    if (j < 3) return qb - 1 + j;
    if (j == 3) return 0;
    if (j == 4) return NB - 1;
    return rb[qb * 3 + (j - 5)];
  };

  auto STAGE = [&](u16* st, int kb) {   // 4 gload16 per wave
    const long krow0 = (long)b * S + kb * 64;
    #pragma unroll
    for (int c = 0; c < 2; ++c) {
      const int n = (w * 2 + c) * 64 + lane;
      const int row = n >> 3;
      const int g2 = (n & 7) ^ (row & 7);
      gload16(k + (krow0 + row) * D + hh * 64 + g2 * 8, st + (w * 2 + c) * 512);
      gload16(vt + vtbase + (long)row * S + kb * 64 + g2 * 8, st + 4096 + (w * 2 + c) * 512);
    }
  };

  f32x4 acc[4];
  #pragma unroll
  for (int nf = 0; nf < 4; ++nf) acc[nf] = (f32x4){0.f, 0.f, 0.f, 0.f};
  f32x4 lacc = (f32x4){0.f, 0.f, 0.f, 0.f};      // row-sums of P (rows = hi*4+r)
  float m_run = -1e30f;                           // my q-row (w*16+lr), log2 domain

  const float C2 = SCALE * L2E;

  float4 mk4[4];
  auto LOADMASK = [&](int kb) {
    const long r = (long)b * S + kb * 64;
    #pragma unroll
    for (int kf = 0; kf < 4; ++kf)
      mk4[kf] = *(const float4*)(mask + r + kf * 16 + hi * 4);
  };

  STAGE(KV[0], kbof(0));
  LOADMASK(kbof(0));

  for (int jj = 0; jj < nkv; ++jj) {
    if (jj + 1 < nkv) {
      STAGE(KV[(jj + 1) & 1], kbof(jj + 1));
      asm volatile("s_waitcnt vmcnt(4)" ::: "memory");
    } else {
      asm volatile("s_waitcnt vmcnt(0)" ::: "memory");
    }
    __builtin_amdgcn_s_barrier();
    __builtin_amdgcn_sched_barrier(0);

    const u16* Ks = KV[jj & 1];
    const u16* Vs = Ks + 4096;

    // ---- QK^T swapped: C[key][q]; sc[kf][r] = score(key=kf*16+hi*4+r, q=w*16+lr)
    f32x4 sc[4];
    #pragma unroll
    for (int kf = 0; kf < 4; ++kf) sc[kf] = (f32x4){0.f, 0.f, 0.f, 0.f};
    __builtin_amdgcn_s_setprio(1);
    #pragma unroll
    for (int kc = 0; kc < 2; ++kc) {
      #pragma unroll
      for (int kf = 0; kf < 4; ++kf) {
        const int g2 = ((kc * 4 + hi) ^ (lr & 7)) << 3;
        bf16x8 kfr = *(const bf16x8*)&Ks[(kf * 16 + lr) * 64 + g2];
        sc[kf] = __builtin_amdgcn_mfma_f32_16x16x32_bf16(kfr, qf[kc], sc[kf], 0, 0, 0);
      }
    }
    __builtin_amdgcn_s_setprio(0);

    // ---- in-lane softmax (exp2 domain); mask preloaded (mk4)
    float sv[4][4];
    float mx = -3.0e38f;
    #pragma unroll
    for (int kf = 0; kf < 4; ++kf) {
      const float mka[4] = {mk4[kf].x, mk4[kf].y, mk4[kf].z, mk4[kf].w};
      #pragma unroll
      for (int r = 0; r < 4; ++r) {
        sv[kf][r] = sc[kf][r] * C2 + (mka[r] - 1.f) * (1e9f * L2E);
        mx = fmaxf(mx, sv[kf][r]);
      }
    }
    mx = fmaxf(mx, __shfl_xor(mx, 16));
    mx = fmaxf(mx, __shfl_xor(mx, 32));
    const bool need = mx > m_run + 8.f;
    if (__any((int)need)) {                 // T13 defer-max
      const float mn = fmaxf(m_run, mx);
      const float al = exp2f(m_run - mn);
      m_run = mn;
      #pragma unroll
      for (int r = 0; r < 4; ++r) {
        const float alr = __shfl(al, (lane & 48) | (hi * 4 + r));
        lacc[r] *= alr;
        acc[0][r] *= alr; acc[1][r] *= alr; acc[2][r] *= alr; acc[3][r] *= alr;
      }
    }
    {
      const int prow = w * 16 + lr;          // my q-row; 4 packed uint2 stores
      #pragma unroll
      for (int kf = 0; kf < 4; ++kf) {
        u32 lo = pack2(exp2f(sv[kf][0] - m_run), exp2f(sv[kf][1] - m_run));
        u32 hi2 = pack2(exp2f(sv[kf][2] - m_run), exp2f(sv[kf][3] - m_run));
        *(uint2*)&Ps[prow][kf * 16 + hi * 4] = make_uint2(lo, hi2);
      }
    }

    // ---- PV + l-sum
    __builtin_amdgcn_s_setprio(1);
    #pragma unroll
    for (int kc = 0; kc < 2; ++kc) {
      bf16x8 pf = *(const bf16x8*)&Ps[w * 16 + lr][kc * 32 + hi * 8];
      #pragma unroll
      for (int nf = 0; nf < 4; ++nf) {
        const int g2 = ((kc * 4 + hi) ^ (lr & 7)) << 3;
        bf16x8 vfr = *(const bf16x8*)&Vs[(nf * 16 + lr) * 64 + g2];
        acc[nf] = __builtin_amdgcn_mfma_f32_16x16x32_bf16(pf, vfr, acc[nf], 0, 0, 0);
      }
      lacc = __builtin_amdgcn_mfma_f32_16x16x32_bf16(pf, ones8, lacc, 0, 0, 0);
    }
    __builtin_amdgcn_s_setprio(0);

    if (jj + 1 < nkv) LOADMASK(kbof(jj + 1));   // prefetch next tile's mask

    __builtin_amdgcn_s_barrier();    // KV[jj&1] reads done; free for next iter's STAGE
  }

  if (!dense) {
    // coalesced ctx store via Ps transpose
    #pragma unroll
    for (int r = 0; r < 4; ++r) {
      const float inv = 1.f / lacc[r];
      const int prow = w * 16 + hi * 4 + r;
      Ps[prow][ 0 + lr] = f2bf(acc[0][r] * inv);
      Ps[prow][16 + lr] = f2bf(acc[1][r] * inv);
      Ps[prow][32 + lr] = f2bf(acc[2][r] * inv);
      Ps[prow][48 + lr] = f2bf(acc[3][r] * inv);
    }
    __syncthreads();
    const int r2 = tid >> 2, c2 = (tid & 3) * 16;
    uint4 v0 = *(const uint4*)&Ps[r2][c2];
    uint4 v1 = *(const uint4*)&Ps[r2][c2 + 8];
    u16* op = ctx + (qrow0 + r2) * D + hh * 64 + c2;
    *(uint4*)(op)     = v0;
    *(uint4*)(op + 8) = v1;
  } else {
    const long pb = ((((long)b * H + hh) * 2 + qb2) * NCH + ch) * (64 * 68);
    #pragma unroll
    for (int r = 0; r < 4; ++r) {
      const float m_r = __shfl(m_run, (lane & 48) | (hi * 4 + r));
      float* pp = part + pb + (w * 16 + hi * 4 + r) * 68;
      pp[ 0 + lr] = acc[0][r];
      pp[16 + lr] = acc[1][r];
      pp[32 + lr] = acc[2][r];
      pp[48 + lr] = acc[3][r];
      if (lr == 0) { pp[64] = m_r; pp[65] = lacc[r]; }  // m in log2 domain
    }
  }
}

// ---------------- combine dense split partials (exp2 domain) ----------------
__global__ __launch_bounds__(256) void attn_combine_kern(
    const float* __restrict__ part, u16* __restrict__ ctx)
{
  const int g = blockIdx.x;
  const int qb2 = g & 1;
  const int hh = (g >> 1) % H;
  const int b  = g / (2 * H);
  const int r  = threadIdx.x >> 2;
  const int d0 = (threadIdx.x & 3) * 16;
  const long pb = (long)g * NCH * 64 * 68;
  float mg = -1e30f;
  for (int ch = 0; ch < NCH; ++ch)
    mg = fmaxf(mg, part[pb + ch * 64 * 68 + r * 68 + 64]);
  float lg = 0.f;
  float a[16] = {};
  for (int ch = 0; ch < NCH; ++ch) {
    const float* pp = part + pb + ch * 64 * 68 + r * 68;
    const float w = exp2f(pp[64] - mg);
    lg += pp[65] * w;
    #pragma unroll
    for (int i = 0; i < 4; ++i) {
      float4 t4 = *(const float4*)(pp + d0 + i * 4);
      a[i*4+0] += t4.x * w; a[i*4+1] += t4.y * w; a[i*4+2] += t4.z * w; a[i*4+3] += t4.w * w;
    }
  }
  const int qb = qb2 ? NB - 1 : 0;
  const float inv = 1.f / lg;
  u16* op = ctx + ((long)b * S + qb * 64 + r) * D + hh * 64 + d0;
  #pragma unroll
  for (int i = 0; i < 4; ++i)
    *(uint2*)(op + i * 4) = make_uint2(pack2(a[i*4+0]*inv, a[i*4+1]*inv),
                                       pack2(a[i*4+2]*inv, a[i*4+3]*inv));
}

// ---------------- span mean-pool + head (bf16 h) ----------------
__global__ __launch_bounds__(256) void span_head_kern(
    const u16* __restrict__ h, const int* __restrict__ spans,
    const float* __restrict__ hw, const float* __restrict__ hb, float* __restrict__ out)
{
  __shared__ float s0[4], s1[4];
  const int bn = blockIdx.x;
  const int tid = threadIdx.x;
  const int st = spans[bn * 2], en = spans[bn * 2 + 1];
  const int b = bn >> 3;
  float a0 = 0.f, a1 = 0.f, a2 = 0.f;
  for (int s = st; s < en; ++s) {
    const u16* row = h + ((long)b * S + s) * D;
    a0 += bf2f(row[tid]); a1 += bf2f(row[tid + 256]); a2 += bf2f(row[tid + 512]);
  }
  const float inv = 1.f / (float)(en - st);
  a0 *= inv; a1 *= inv; a2 *= inv;
  float p0 = a0 * hw[tid * 2]     + a1 * hw[(tid + 256) * 2]     + a2 * hw[(tid + 512) * 2];
  float p1 = a0 * hw[tid * 2 + 1] + a1 * hw[(tid + 256) * 2 + 1] + a2 * hw[(tid + 512) * 2 + 1];
  #pragma unroll
  for (int o = 32; o; o >>= 1) { p0 += __shfl_xor(p0, o); p1 += __shfl_xor(p1, o); }
  if ((tid & 63) == 0) { s0[tid >> 6] = p0; s1[tid >> 6] = p1; }
  __syncthreads();
  if (tid == 0) {
    out[bn * 2]     = s0[0] + s0[1] + s0[2] + s0[3] + hb[0];
    out[bn * 2 + 1] = s1[0] + s1[1] + s1[2] + s1[3] + hb[1];
  }
}

// ---------------- launcher ----------------
extern "C" void kernel_launch(void* const* d_in, const int* in_sizes, int n_in,
                              void* d_out, int out_size, void* d_ws, size_t ws_size,
                              hipStream_t stream) {
  const int*   input_ids  = (const int*)  d_in[0];
  const float* attn_mask  = (const float*)d_in[1];
  const int*   tok_type   = (const int*)  d_in[2];
  const int*   spans      = (const int*)  d_in[3];
  const int*   rand_blk   = (const int*)  d_in[4];
  const float* word_emb   = (const float*)d_in[5];
  const float* pos_emb    = (const float*)d_in[6];
  const float* type_emb   = (const float*)d_in[7];
  const float* emb_g      = (const float*)d_in[8];
  const float* emb_b      = (const float*)d_in[9];
  const float* qkv_w      = (const float*)d_in[10];
  const float* qkv_b      = (const float*)d_in[11];
  const float* aow        = (const float*)d_in[12];
  const float* aob        = (const float*)d_in[13];
  const float* ln1g       = (const float*)d_in[14];
  const float* ln1b       = (const float*)d_in[15];
  const float* ff1w       = (const float*)d_in[16];
  const float* ff1b       = (const float*)d_in[17];
  const float* ff2w       = (const float*)d_in[18];
  const float* ff2b       = (const float*)d_in[19];
  const float* ln2g       = (const float*)d_in[20];
  const float* ln2b       = (const float*)d_in[21];
  const float* headw      = (const float*)d_in[22];
  const float* headb      = (const float*)d_in[23];

  float* ws    = (float*)d_ws;
  u16*   h     = (u16*)ws;                    // [M,D] bf16 residual stream
  u16*   qkvb  = (u16*)(ws + HD);             // q,k bf16 [M,D]; vt [B,H,64,S]
  u16*   ffb   = (u16*)(ws + HD);             // [M,F] bf16 overlays qkv region
  u16*   ctx16 = (u16*)(ws + 3 * HD);         // [M,D] bf16
  float* part  = ws + 4 * HD;                 // dense partials: 2*12*2*8*64*68 ~1.67M floats
  u16*   wb    = (u16*)(ws + 4 * HD + HD/2);  // bf16 weights: [qkv6][ao2][ff1x2][ff2x2]

  // ---- weight prep (bf16 transposed), z-batched across both layers: 4 launches ----
  wtrans_kern<<<dim3(24, 24, 6), dim3(256), 0, stream>>>(qkv_w, wb, D, D, DD, DD);
  wtrans_kern<<<dim3(24, 24, 2), dim3(256), 0, stream>>>(aow, wb + OFF_AO, D, D, DD, DD);
  wtrans_kern<<<dim3(96, 24, 2), dim3(256), 0, stream>>>(ff1w, wb + OFF_FF1, D, F, DF, DF);
  wtrans_kern<<<dim3(24, 96, 2), dim3(256), 0, stream>>>(ff2w, wb + OFF_FF2, F, D, DF, DF);

  embed_ln_kern<<<dim3(M / 4), dim3(256), 0, stream>>>(
      input_ids, tok_type, word_emb, pos_emb, type_emb, emb_g, emb_b, h);

  for (int l = 0; l < 2; ++l) {
    // merged QKV projection (N=2304): q,k coalesced bf16; v transposed [b,h,d,S]
    mgemm_kern<<<dim3(18, 64, 1), dim3(256), 0, stream>>>(
        h, wb + (long)l * 3 * DD, qkv_b + (long)l * 3 * D, qkvb, 2304, D, 0, 0, 0, 4, 1);
    // block attention: 1D XCD-chunked grid (sparse 62 + dense 16 per (b,h), 8 tiles each)
    mattn_kern<<<dim3(1872), dim3(256), 0, stream>>>(
        qkvb, qkvb + HD, qkvb + 2 * HD, attn_mask, rand_blk, ctx16, part);
    attn_combine_kern<<<dim3(B * H * 2), dim3(256), 0, stream>>>(part, ctx16);
    // output projection + bf16 residual add into h (coalesced RMW)
    mgemm_kern<<<dim3(6, 64, 1), dim3(256), 0, stream>>>(
        ctx16, wb + OFF_AO + (long)l * DD, aob + (long)l * D, h, D, D, 0, 0, 0, 2, 1);
    ln_kern<<<dim3(M / 4), dim3(256), 0, stream>>>(h, ln1g + (long)l * D, ln1b + (long)l * D);
    // FFN
    mgemm_kern<<<dim3(24, 64, 1), dim3(256), 0, stream>>>(
        h, wb + OFF_FF1 + (long)l * DF, ff1b + (long)l * F, ffb, F, D, 0, 0, 0, 1, 1);
    mgemm_kern<<<dim3(6, 64, 1), dim3(256), 0, stream>>>(
        ffb, wb + OFF_FF2 + (long)l * DF, ff2b + (long)l * D, h, D, F, 0, 0, 0, 2, 1);
    ln_kern<<<dim3(M / 4), dim3(256), 0, stream>>>(h, ln2g + (long)l * D, ln2b + (long)l * D);
  }

  span_head_kern<<<dim3(B * NS), dim3(256), 0, stream>>>(h, spans, headw, headb, (float*)d_out);
}